// Round 9
// baseline (1163.501 us; speedup 1.0000x reference)
//
#include <hip/hip_runtime.h>

#define BN_EPS 1e-5f
#define CHUNK 4096
#define MAXB 512   // max buckets (N up to 131072 with 256 nodes/bucket)
#define NCB 512    // count blocks in K1

// bf16 helpers (RNE pack, cheap unpack)
__device__ __forceinline__ unsigned short f2bf(float f) {
    unsigned int u = __float_as_uint(f);
    u += 0x7FFF + ((u >> 16) & 1);
    return (unsigned short)(u >> 16);
}
__device__ __forceinline__ float bf2f(unsigned short h) {
    return __uint_as_float((unsigned int)h << 16);
}

// ================= K1: bin_count (+last-block scan) fused with linear =================
// blocks [0,NCB): LDS histogram of dst>>8 -> global atomic bcnt; the LAST count block
// to finish (fence + device-scope counter, no waiting/residency assumption) scans
// bcnt -> boff/bpos. blocks [NCB, NCB+2048): Y[n][64](bf16) = X[n][128] @ W^T.
__global__ __launch_bounds__(256) void k1_count_scan_linear(
    const int* __restrict__ ei, int E,
    const float* __restrict__ X, const float* __restrict__ W,
    int* __restrict__ bcnt, int* __restrict__ boff, int* __restrict__ bpos,
    int* __restrict__ done, unsigned short* __restrict__ Y, int N, int nbuck) {
    __shared__ float lds[10240];  // 40KB union
    int tid = threadIdx.x;
    if (blockIdx.x < NCB) {
        int* h = (int*)lds;
        for (int i = tid; i < MAXB; i += 256) h[i] = 0;
        __syncthreads();
        for (int e = blockIdx.x * 256 + tid; e < E; e += NCB * 256)
            atomicAdd(&h[ei[E + e] >> 8], 1);
        __syncthreads();
        for (int b = tid; b < nbuck; b += 256)
            if (h[b]) atomicAdd(&bcnt[b], h[b]);
        __threadfence();
        __shared__ int last;
        if (tid == 0) {
            int old = __hip_atomic_fetch_add(done, 1, __ATOMIC_ACQ_REL, __HIP_MEMORY_SCOPE_AGENT);
            last = (old == NCB - 1);
        }
        __syncthreads();
        if (!last) return;
        __threadfence();
        // last block: exclusive scan of bcnt[0..nbuck), 2 entries/thread
        int a0 = (2 * tid < nbuck) ? bcnt[2 * tid] : 0;
        int a1 = (2 * tid + 1 < nbuck) ? bcnt[2 * tid + 1] : 0;
        int tot = a0 + a1;
        int lane = tid & 63, wv = tid >> 6;
        int s = tot;
#pragma unroll
        for (int off = 1; off < 64; off <<= 1) {
            int t = __shfl_up(s, off, 64);
            if (lane >= off) s += t;
        }
        int* wsum = (int*)lds;
        if (lane == 63) wsum[wv] = s;
        __syncthreads();
        int woff = 0;
#pragma unroll
        for (int i = 0; i < 4; i++) woff += (i < wv) ? wsum[i] : 0;
        int excl = woff + s - tot;
        if (2 * tid < nbuck) { boff[2 * tid] = excl; bpos[2 * tid] = excl; }
        if (2 * tid + 1 < nbuck) { boff[2 * tid + 1] = excl + a0; bpos[2 * tid + 1] = excl + a0; }
        if (tid == 0) boff[nbuck] = E;
        return;
    }
    // ---- linear part: R8-proven body, grid-strided over 2048 virtual blocks ----
    int bidx = blockIdx.x - NCB;
    float* wlds = lds;          // 8192 floats
    float* xlds = lds + 8192;   // 2048 floats
    for (int j = tid; j < 64 * 128; j += 256) {
        int o = j >> 7, k = j & 127;
        wlds[(k >> 2) * 256 + o * 4 + (k & 3)] = W[j];
    }
    __syncthreads();
    const float4* w4p = (const float4*)wlds;
    const float4* x4p = (const float4*)xlds;
    int wv = tid >> 6, lane = tid & 63;
    for (int nb = bidx * 16; nb < N; nb += 2048 * 16) {
        const float4* xg = (const float4*)(X + (size_t)nb * 128);
        float4* xl = (float4*)xlds;
        for (int j = tid; j < 512; j += 256) xl[j] = xg[j];
        __syncthreads();
        int r = wv * 4;
        float a0 = 0.f, a1 = 0.f, a2 = 0.f, a3 = 0.f;
#pragma unroll 8
        for (int kb = 0; kb < 32; kb++) {
            float4 w = w4p[kb * 64 + lane];
            float4 x0 = x4p[(r + 0) * 32 + kb];
            float4 x1 = x4p[(r + 1) * 32 + kb];
            float4 x2 = x4p[(r + 2) * 32 + kb];
            float4 x3 = x4p[(r + 3) * 32 + kb];
            a0 += x0.x * w.x + x0.y * w.y + x0.z * w.z + x0.w * w.w;
            a1 += x1.x * w.x + x1.y * w.y + x1.z * w.z + x1.w * w.w;
            a2 += x2.x * w.x + x2.y * w.y + x2.z * w.z + x2.w * w.w;
            a3 += x3.x * w.x + x3.y * w.y + x3.z * w.z + x3.w * w.w;
        }
        Y[(size_t)(nb + r + 0) * 64 + lane] = f2bf(a0);
        Y[(size_t)(nb + r + 1) * 64 + lane] = f2bf(a1);
        Y[(size_t)(nb + r + 2) * 64 + lane] = f2bf(a2);
        Y[(size_t)(nb + r + 3) * 64 + lane] = f2bf(a3);
        __syncthreads();
    }
}

// ================= K2: bin_scatter + grid spin-sync + bucket_csr =================
// grid = max(nchunk, nbuck) = 391 blocks, 256 thr, 4KB LDS -> trivially co-resident.
__global__ __launch_bounds__(256) void k2_scatter_csr(
    const int* __restrict__ ei, int E, int* __restrict__ bpos,
    int* __restrict__ binned, const int* __restrict__ boff,
    int* __restrict__ row_ptr, int* __restrict__ esrc,
    int* __restrict__ done, int N, int nbuck, int nchunk) {
    __shared__ int h[MAXB];
    __shared__ int res[MAXB];
    __shared__ int wsum[4];
    int tid = threadIdx.x, b = blockIdx.x;
    if (b < nchunk) {
        int base = b * CHUNK;
        int cnt = min(CHUNK, E - base);
        for (int i = tid; i < nbuck; i += 256) h[i] = 0;
        __syncthreads();
        for (int k = tid; k < cnt; k += 256) atomicAdd(&h[ei[E + base + k] >> 8], 1);
        __syncthreads();
        for (int i = tid; i < nbuck; i += 256) {
            int c = h[i];
            res[i] = c ? atomicAdd(&bpos[i], c) : 0;
            h[i] = 0;  // reuse as rank counter
        }
        __syncthreads();
        for (int k = tid; k < cnt; k += 256) {
            int srcv = ei[base + k];
            int d = ei[E + base + k];
            int bb = d >> 8;
            int r = atomicAdd(&h[bb], 1);
            binned[res[bb] + r] = ((d & 255) << 17) | srcv;  // src < 2^17
        }
    }
    // ---- grid sync: all binned writes drained, visible device-wide ----
    __syncthreads();
    __threadfence();
    if (tid == 0) {
        __hip_atomic_fetch_add(done, 1, __ATOMIC_ACQ_REL, __HIP_MEMORY_SCOPE_AGENT);
        while (__hip_atomic_load(done, __ATOMIC_ACQUIRE, __HIP_MEMORY_SCOPE_AGENT) < (int)gridDim.x)
            __builtin_amdgcn_s_sleep(2);
    }
    __syncthreads();
    __threadfence();
    if (b >= nbuck) return;
    // ---- bucket_csr phase (R4-proven 256-thr body) ----
    int lo = boff[b], hi = boff[b + 1];
    int base_node = b << 8;
    int lane = tid & 63, wv = tid >> 6;
    h[tid] = 0;
    __syncthreads();
    for (int i = lo + tid; i < hi; i += 256) atomicAdd(&h[binned[i] >> 17], 1);
    __syncthreads();
    int c = h[tid];
    int s = c;
#pragma unroll
    for (int off = 1; off < 64; off <<= 1) {
        int t = __shfl_up(s, off, 64);
        if (lane >= off) s += t;
    }
    if (lane == 63) wsum[wv] = s;
    __syncthreads();
    int woff = 0;
#pragma unroll
    for (int i = 0; i < 4; i++) woff += (i < wv) ? wsum[i] : 0;
    int abspos = lo + woff + (s - c);
    if (base_node + tid < N) row_ptr[base_node + tid] = abspos;
    res[tid] = abspos;
    __syncthreads();
    for (int i = lo + tid; i < hi; i += 256) {
        int val = binned[i];
        int r = atomicAdd(&res[val >> 17], 1);
        esrc[r] = val & 0x1FFFF;
    }
    if (b == 0 && tid == 0) row_ptr[N] = E;
}

// ================= gather fused with 2-matrix MLP (layer-1 full pipeline) =================
// per wave: gather 4 nodes (t = relu(Y[i]+aggr+ba)) into wave-private LDS tile,
// then y2 = (relu(bn(t@W1^T+b1)))@W2^T, write bf16. No __syncthreads in the loop.
__global__ __launch_bounds__(256) void gather_mlp2(
    const unsigned short* __restrict__ Y, const int* __restrict__ row_ptr,
    const int* __restrict__ esrc, const float* __restrict__ ba,
    const float* __restrict__ W1, const float* __restrict__ b1,
    const float* __restrict__ g, const float* __restrict__ be,
    const float* __restrict__ m, const float* __restrict__ v,
    const float* __restrict__ W2, unsigned short* __restrict__ O, int N) {
    __shared__ float w1lds[4096];
    __shared__ float w2lds[4096];
    __shared__ float tl[4][256];
    __shared__ float hl[4][256];
    int tid = threadIdx.x, wv = tid >> 6, lane = tid & 63;
    for (int j = tid; j < 4096; j += 256) {
        int o = j >> 6, k = j & 63;
        int idx = (k >> 2) * 256 + o * 4 + (k & 3);
        w1lds[idx] = W1[j];
        w2lds[idx] = W2[j];
    }
    float biasA = ba[lane];
    float bias1 = b1[lane];
    float s = g[lane] * rsqrtf(v[lane] + BN_EPS);
    float c = be[lane] - m[lane] * s;
    __syncthreads();
    const float4* w14 = (const float4*)w1lds;
    const float4* w24 = (const float4*)w2lds;
    const float4* t4 = (const float4*)tl[wv];
    const float4* h4 = (const float4*)hl[wv];
    int gw = blockIdx.x * 4 + wv;
    int stride = gridDim.x * 16;  // waves * 4 nodes
    for (int base = gw * 4; base < N; base += stride) {
        for (int j = 0; j < 4; j++) {
            int node = base + j;
            float t = 0.f;
            if (node < N) {
                float acc = bf2f(Y[(size_t)node * 64 + lane]) + biasA;
                int e = row_ptr[node], e1 = row_ptr[node + 1];
                for (; e + 8 <= e1; e += 8) {
                    int s0 = esrc[e], s1 = esrc[e + 1], s2 = esrc[e + 2], s3 = esrc[e + 3];
                    int s4 = esrc[e + 4], s5 = esrc[e + 5], s6 = esrc[e + 6], s7 = esrc[e + 7];
                    float f0 = bf2f(Y[(size_t)s0 * 64 + lane]);
                    float f1 = bf2f(Y[(size_t)s1 * 64 + lane]);
                    float f2 = bf2f(Y[(size_t)s2 * 64 + lane]);
                    float f3 = bf2f(Y[(size_t)s3 * 64 + lane]);
                    float f4 = bf2f(Y[(size_t)s4 * 64 + lane]);
                    float f5 = bf2f(Y[(size_t)s5 * 64 + lane]);
                    float f6 = bf2f(Y[(size_t)s6 * 64 + lane]);
                    float f7 = bf2f(Y[(size_t)s7 * 64 + lane]);
                    acc += ((f0 + f1) + (f2 + f3)) + ((f4 + f5) + (f6 + f7));
                }
                for (; e < e1; e++) acc += bf2f(Y[(size_t)esrc[e] * 64 + lane]);
                t = fmaxf(acc, 0.f);
            }
            tl[wv][j * 64 + lane] = t;  // wave-private, no barrier needed
        }
        float a0 = bias1, a1 = bias1, a2 = bias1, a3 = bias1;
#pragma unroll
        for (int kb = 0; kb < 16; kb++) {
            float4 w = w14[kb * 64 + lane];
            float4 x0 = t4[0 * 16 + kb];
            float4 x1 = t4[1 * 16 + kb];
            float4 x2 = t4[2 * 16 + kb];
            float4 x3 = t4[3 * 16 + kb];
            a0 += x0.x * w.x + x0.y * w.y + x0.z * w.z + x0.w * w.w;
            a1 += x1.x * w.x + x1.y * w.y + x1.z * w.z + x1.w * w.w;
            a2 += x2.x * w.x + x2.y * w.y + x2.z * w.z + x2.w * w.w;
            a3 += x3.x * w.x + x3.y * w.y + x3.z * w.z + x3.w * w.w;
        }
        a0 = fmaxf(a0 * s + c, 0.f);
        a1 = fmaxf(a1 * s + c, 0.f);
        a2 = fmaxf(a2 * s + c, 0.f);
        a3 = fmaxf(a3 * s + c, 0.f);
        hl[wv][0 * 64 + lane] = a0;
        hl[wv][1 * 64 + lane] = a1;
        hl[wv][2 * 64 + lane] = a2;
        hl[wv][3 * 64 + lane] = a3;
        float o0 = 0.f, o1 = 0.f, o2 = 0.f, o3 = 0.f;
#pragma unroll
        for (int kb = 0; kb < 16; kb++) {
            float4 w = w24[kb * 64 + lane];
            float4 x0 = h4[0 * 16 + kb];
            float4 x1 = h4[1 * 16 + kb];
            float4 x2 = h4[2 * 16 + kb];
            float4 x3 = h4[3 * 16 + kb];
            o0 += x0.x * w.x + x0.y * w.y + x0.z * w.z + x0.w * w.w;
            o1 += x1.x * w.x + x1.y * w.y + x1.z * w.z + x1.w * w.w;
            o2 += x2.x * w.x + x2.y * w.y + x2.z * w.z + x2.w * w.w;
            o3 += x3.x * w.x + x3.y * w.y + x3.z * w.z + x3.w * w.w;
        }
        if (base + 0 < N) O[(size_t)(base + 0) * 64 + lane] = f2bf(o0);
        if (base + 1 < N) O[(size_t)(base + 1) * 64 + lane] = f2bf(o1);
        if (base + 2 < N) O[(size_t)(base + 2) * 64 + lane] = f2bf(o2);
        if (base + 3 < N) O[(size_t)(base + 3) * 64 + lane] = f2bf(o3);
    }
}

// ================= gather fused with 1-matrix MLP+BN (layer-2 tail) =================
// H[i] = relu(bn(t@W^T + b)), t = relu(Y[i]+aggr+ba). 20KB LDS -> 8 blocks/CU.
__global__ __launch_bounds__(256) void gather_mlp1(
    const unsigned short* __restrict__ Y, const int* __restrict__ row_ptr,
    const int* __restrict__ esrc, const float* __restrict__ ba,
    const float* __restrict__ W, const float* __restrict__ b,
    const float* __restrict__ g, const float* __restrict__ be,
    const float* __restrict__ m, const float* __restrict__ v,
    unsigned short* __restrict__ H, int N) {
    __shared__ float wlds[4096];
    __shared__ float tl[4][256];
    int tid = threadIdx.x, wv = tid >> 6, lane = tid & 63;
    for (int j = tid; j < 4096; j += 256) {
        int o = j >> 6, k = j & 63;
        wlds[(k >> 2) * 256 + o * 4 + (k & 3)] = W[j];
    }
    float biasA = ba[lane];
    float bias1 = b[lane];
    float s = g[lane] * rsqrtf(v[lane] + BN_EPS);
    float c = be[lane] - m[lane] * s;
    __syncthreads();
    const float4* w4 = (const float4*)wlds;
    const float4* t4 = (const float4*)tl[wv];
    int gw = blockIdx.x * 4 + wv;
    int stride = gridDim.x * 16;
    for (int base = gw * 4; base < N; base += stride) {
        for (int j = 0; j < 4; j++) {
            int node = base + j;
            float t = 0.f;
            if (node < N) {
                float acc = bf2f(Y[(size_t)node * 64 + lane]) + biasA;
                int e = row_ptr[node], e1 = row_ptr[node + 1];
                for (; e + 8 <= e1; e += 8) {
                    int s0 = esrc[e], s1 = esrc[e + 1], s2 = esrc[e + 2], s3 = esrc[e + 3];
                    int s4 = esrc[e + 4], s5 = esrc[e + 5], s6 = esrc[e + 6], s7 = esrc[e + 7];
                    float f0 = bf2f(Y[(size_t)s0 * 64 + lane]);
                    float f1 = bf2f(Y[(size_t)s1 * 64 + lane]);
                    float f2 = bf2f(Y[(size_t)s2 * 64 + lane]);
                    float f3 = bf2f(Y[(size_t)s3 * 64 + lane]);
                    float f4 = bf2f(Y[(size_t)s4 * 64 + lane]);
                    float f5 = bf2f(Y[(size_t)s5 * 64 + lane]);
                    float f6 = bf2f(Y[(size_t)s6 * 64 + lane]);
                    float f7 = bf2f(Y[(size_t)s7 * 64 + lane]);
                    acc += ((f0 + f1) + (f2 + f3)) + ((f4 + f5) + (f6 + f7));
                }
                for (; e < e1; e++) acc += bf2f(Y[(size_t)esrc[e] * 64 + lane]);
                t = fmaxf(acc, 0.f);
            }
            tl[wv][j * 64 + lane] = t;
        }
        float a0 = bias1, a1 = bias1, a2 = bias1, a3 = bias1;
#pragma unroll
        for (int kb = 0; kb < 16; kb++) {
            float4 w = w4[kb * 64 + lane];
            float4 x0 = t4[0 * 16 + kb];
            float4 x1 = t4[1 * 16 + kb];
            float4 x2 = t4[2 * 16 + kb];
            float4 x3 = t4[3 * 16 + kb];
            a0 += x0.x * w.x + x0.y * w.y + x0.z * w.z + x0.w * w.w;
            a1 += x1.x * w.x + x1.y * w.y + x1.z * w.z + x1.w * w.w;
            a2 += x2.x * w.x + x2.y * w.y + x2.z * w.z + x2.w * w.w;
            a3 += x3.x * w.x + x3.y * w.y + x3.z * w.z + x3.w * w.w;
        }
        if (base + 0 < N) H[(size_t)(base + 0) * 64 + lane] = f2bf(fmaxf(a0 * s + c, 0.f));
        if (base + 1 < N) H[(size_t)(base + 1) * 64 + lane] = f2bf(fmaxf(a1 * s + c, 0.f));
        if (base + 2 < N) H[(size_t)(base + 2) * 64 + lane] = f2bf(fmaxf(a2 * s + c, 0.f));
        if (base + 3 < N) H[(size_t)(base + 3) * 64 + lane] = f2bf(fmaxf(a3 * s + c, 0.f));
    }
}

// ---------------- mean pool per graph (batch is sorted) ----------------
__global__ __launch_bounds__(256) void pool_kernel(const unsigned short* __restrict__ H,
                                                   const int* __restrict__ batch,
                                                   float* __restrict__ out, int N) {
    __shared__ float part[4][64];
    int g = blockIdx.x;
    int tid = threadIdx.x, wv = tid >> 6, lane = tid & 63;
    int lo = 0, hi = N;
    while (lo < hi) { int mid = (lo + hi) >> 1; if (batch[mid] < g) lo = mid + 1; else hi = mid; }
    int start = lo;
    hi = N;
    while (lo < hi) { int mid = (lo + hi) >> 1; if (batch[mid] < g + 1) lo = mid + 1; else hi = mid; }
    int end = lo;
    float acc = 0.f;
    for (int i = start + wv; i < end; i += 4) acc += bf2f(H[(size_t)i * 64 + lane]);
    part[wv][lane] = acc;
    __syncthreads();
    if (tid < 64) {
        float sfin = part[0][tid] + part[1][tid] + part[2][tid] + part[3][tid];
        float cnt = (float)(end - start);
        out[(size_t)g * 64 + tid] = sfin / fmaxf(cnt, 1.f);
    }
}

extern "C" void kernel_launch(void* const* d_in, const int* in_sizes, int n_in,
                              void* d_out, int out_size, void* d_ws, size_t ws_size,
                              hipStream_t stream) {
    const float* x   = (const float*)d_in[0];
    const int*   ei  = (const int*)d_in[1];
    const int*   bat = (const int*)d_in[2];
    const float* W1a = (const float*)d_in[3];
    const float* b1a = (const float*)d_in[4];
    const float* W1b = (const float*)d_in[5];
    const float* b1b = (const float*)d_in[6];
    const float* g1  = (const float*)d_in[7];
    const float* be1 = (const float*)d_in[8];
    const float* m1  = (const float*)d_in[9];
    const float* v1  = (const float*)d_in[10];
    const float* W2a = (const float*)d_in[11];
    const float* b2a = (const float*)d_in[12];
    const float* W2b = (const float*)d_in[13];
    const float* b2b = (const float*)d_in[14];
    const float* g2  = (const float*)d_in[15];
    const float* be2 = (const float*)d_in[16];
    const float* m2  = (const float*)d_in[17];
    const float* v2  = (const float*)d_in[18];
    float* out = (float*)d_out;

    int N = in_sizes[0] / 128;
    int E = in_sizes[1] / 2;
    int G = out_size / 64;
    int nbuck = (N + 255) >> 8;
    int nchunk = (E + CHUNK - 1) / CHUNK;
    int grid2 = (nchunk > nbuck) ? nchunk : nbuck;

    // workspace layout
    char* ws = (char*)d_ws;
    int* done = (int*)ws;                                 // 4 (done[0]=K1, done[1]=K2)
    int* bcnt = done + 4;                                 // MAXB
    int* boff = bcnt + MAXB;                              // MAXB+4
    int* bpos = boff + MAXB + 4;                          // MAXB
    int* row_ptr = bpos + MAXB;                           // N+1 (padded)
    int* esrc = row_ptr + ((N + 2 + 3) & ~3);             // E
    int* binned = esrc + E;                               // E
    unsigned short* bufA = (unsigned short*)(binned + E); // N*64 bf16
    unsigned short* bufB = bufA + (size_t)N * 64;         // N*64 bf16

    // one memset zeroes done counters + bcnt (contiguous)
    hipMemsetAsync(done, 0, (4 + MAXB) * sizeof(int), stream);

    // K1: histogram + last-block scan + linear (x @ W1a^T -> bufA)
    k1_count_scan_linear<<<NCB + 2048, 256, 0, stream>>>(ei, E, x, W1a, bcnt, boff, bpos,
                                                         done, bufA, N, nbuck);
    // K2: bin_scatter + grid sync + bucket_csr -> row_ptr/esrc
    k2_scatter_csr<<<grid2, 256, 0, stream>>>(ei, E, bpos, binned, boff, row_ptr, esrc,
                                              done + 1, N, nbuck, nchunk);
    // layer 1: gather + MLP2 (bufA -> bufB)
    gather_mlp2<<<2048, 256, 0, stream>>>(bufA, row_ptr, esrc, b1a, W1b, b1b,
                                          g1, be1, m1, v1, W2a, bufB, N);
    // layer 2: gather + MLP1+BN (bufB -> bufA)
    gather_mlp1<<<2048, 256, 0, stream>>>(bufB, row_ptr, esrc, b2a, W2b, b2b,
                                          g2, be2, m2, v2, bufA, N);
    // mean pool
    pool_kernel<<<G, 256, 0, stream>>>(bufA, bat, out, N);
}

// Round 10
// 659.469 us; speedup vs baseline: 1.7643x; 1.7643x over previous
//
#include <hip/hip_runtime.h>

#define BN_EPS 1e-5f
#define CHUNK 4096
#define MAXB 512   // max buckets (N up to 131072 with 256 nodes/bucket)
#define NCB 512    // count blocks in K1

// bf16 helpers (RNE pack, cheap unpack)
__device__ __forceinline__ unsigned short f2bf(float f) {
    unsigned int u = __float_as_uint(f);
    u += 0x7FFF + ((u >> 16) & 1);
    return (unsigned short)(u >> 16);
}
__device__ __forceinline__ float bf2f(unsigned short h) {
    return __uint_as_float((unsigned int)h << 16);
}

// ================= K1: bin_count (+last-block scan) fused with linear =================
// blocks [0,NCB): LDS histogram of dst>>8 -> global atomic bcnt; LAST count block
// (fence + device-scope counter, no co-residency assumption) scans bcnt -> boff/bpos.
// blocks [NCB, NCB+2048): Y[n][64](bf16) = X[n][128] @ W^T (R8-proven body).
__global__ __launch_bounds__(256) void k1_count_scan_linear(
    const int* __restrict__ ei, int E,
    const float* __restrict__ X, const float* __restrict__ W,
    int* __restrict__ bcnt, int* __restrict__ boff, int* __restrict__ bpos,
    int* __restrict__ done, unsigned short* __restrict__ Y, int N, int nbuck) {
    __shared__ float lds[10240];  // 40KB union
    int tid = threadIdx.x;
    if (blockIdx.x < NCB) {
        int* h = (int*)lds;
        for (int i = tid; i < MAXB; i += 256) h[i] = 0;
        __syncthreads();
        for (int e = blockIdx.x * 256 + tid; e < E; e += NCB * 256)
            atomicAdd(&h[ei[E + e] >> 8], 1);
        __syncthreads();
        for (int b = tid; b < nbuck; b += 256)
            if (h[b]) atomicAdd(&bcnt[b], h[b]);
        __threadfence();
        __shared__ int last;
        if (tid == 0) {
            int old = __hip_atomic_fetch_add(done, 1, __ATOMIC_ACQ_REL, __HIP_MEMORY_SCOPE_AGENT);
            last = (old == NCB - 1);
        }
        __syncthreads();
        if (!last) return;
        __threadfence();
        int a0 = (2 * tid < nbuck) ? bcnt[2 * tid] : 0;
        int a1 = (2 * tid + 1 < nbuck) ? bcnt[2 * tid + 1] : 0;
        int tot = a0 + a1;
        int lane = tid & 63, wv = tid >> 6;
        int s = tot;
#pragma unroll
        for (int off = 1; off < 64; off <<= 1) {
            int t = __shfl_up(s, off, 64);
            if (lane >= off) s += t;
        }
        int* wsum = (int*)lds;
        if (lane == 63) wsum[wv] = s;
        __syncthreads();
        int woff = 0;
#pragma unroll
        for (int i = 0; i < 4; i++) woff += (i < wv) ? wsum[i] : 0;
        int excl = woff + s - tot;
        if (2 * tid < nbuck) { boff[2 * tid] = excl; bpos[2 * tid] = excl; }
        if (2 * tid + 1 < nbuck) { boff[2 * tid + 1] = excl + a0; bpos[2 * tid + 1] = excl + a0; }
        if (tid == 0) boff[nbuck] = E;
        return;
    }
    // ---- linear part ----
    int bidx = blockIdx.x - NCB;
    float* wlds = lds;          // 8192 floats
    float* xlds = lds + 8192;   // 2048 floats
    for (int j = tid; j < 64 * 128; j += 256) {
        int o = j >> 7, k = j & 127;
        wlds[(k >> 2) * 256 + o * 4 + (k & 3)] = W[j];
    }
    __syncthreads();
    const float4* w4p = (const float4*)wlds;
    const float4* x4p = (const float4*)xlds;
    int wv = tid >> 6, lane = tid & 63;
    for (int nb = bidx * 16; nb < N; nb += 2048 * 16) {
        const float4* xg = (const float4*)(X + (size_t)nb * 128);
        float4* xl = (float4*)xlds;
        for (int j = tid; j < 512; j += 256) xl[j] = xg[j];
        __syncthreads();
        int r = wv * 4;
        float a0 = 0.f, a1 = 0.f, a2 = 0.f, a3 = 0.f;
#pragma unroll 8
        for (int kb = 0; kb < 32; kb++) {
            float4 w = w4p[kb * 64 + lane];
            float4 x0 = x4p[(r + 0) * 32 + kb];
            float4 x1 = x4p[(r + 1) * 32 + kb];
            float4 x2 = x4p[(r + 2) * 32 + kb];
            float4 x3 = x4p[(r + 3) * 32 + kb];
            a0 += x0.x * w.x + x0.y * w.y + x0.z * w.z + x0.w * w.w;
            a1 += x1.x * w.x + x1.y * w.y + x1.z * w.z + x1.w * w.w;
            a2 += x2.x * w.x + x2.y * w.y + x2.z * w.z + x2.w * w.w;
            a3 += x3.x * w.x + x3.y * w.y + x3.z * w.z + x3.w * w.w;
        }
        Y[(size_t)(nb + r + 0) * 64 + lane] = f2bf(a0);
        Y[(size_t)(nb + r + 1) * 64 + lane] = f2bf(a1);
        Y[(size_t)(nb + r + 2) * 64 + lane] = f2bf(a2);
        Y[(size_t)(nb + r + 3) * 64 + lane] = f2bf(a3);
        __syncthreads();
    }
}

// ================= K2: bin_scatter + grid spin-sync + bucket_csr =================
// grid = max(nchunk, nbuck) = 391 blocks, 256 thr, 4KB LDS -> trivially co-resident.
__global__ __launch_bounds__(256) void k2_scatter_csr(
    const int* __restrict__ ei, int E, int* __restrict__ bpos,
    int* __restrict__ binned, const int* __restrict__ boff,
    int* __restrict__ row_ptr, int* __restrict__ esrc,
    int* __restrict__ done, int N, int nbuck, int nchunk) {
    __shared__ int h[MAXB];
    __shared__ int res[MAXB];
    __shared__ int wsum[4];
    int tid = threadIdx.x, b = blockIdx.x;
    if (b < nchunk) {
        int base = b * CHUNK;
        int cnt = min(CHUNK, E - base);
        for (int i = tid; i < nbuck; i += 256) h[i] = 0;
        __syncthreads();
        for (int k = tid; k < cnt; k += 256) atomicAdd(&h[ei[E + base + k] >> 8], 1);
        __syncthreads();
        for (int i = tid; i < nbuck; i += 256) {
            int c = h[i];
            res[i] = c ? atomicAdd(&bpos[i], c) : 0;
            h[i] = 0;  // reuse as rank counter
        }
        __syncthreads();
        for (int k = tid; k < cnt; k += 256) {
            int srcv = ei[base + k];
            int d = ei[E + base + k];
            int bb = d >> 8;
            int r = atomicAdd(&h[bb], 1);
            binned[res[bb] + r] = ((d & 255) << 17) | srcv;  // src < 2^17
        }
    }
    // ---- grid sync ----
    __syncthreads();
    __threadfence();
    if (tid == 0) {
        __hip_atomic_fetch_add(done, 1, __ATOMIC_ACQ_REL, __HIP_MEMORY_SCOPE_AGENT);
        while (__hip_atomic_load(done, __ATOMIC_ACQUIRE, __HIP_MEMORY_SCOPE_AGENT) < (int)gridDim.x)
            __builtin_amdgcn_s_sleep(2);
    }
    __syncthreads();
    __threadfence();
    if (b >= nbuck) return;
    // ---- bucket_csr phase ----
    int lo = boff[b], hi = boff[b + 1];
    int base_node = b << 8;
    int lane = tid & 63, wv = tid >> 6;
    h[tid] = 0;
    __syncthreads();
    for (int i = lo + tid; i < hi; i += 256) atomicAdd(&h[binned[i] >> 17], 1);
    __syncthreads();
    int c = h[tid];
    int s = c;
#pragma unroll
    for (int off = 1; off < 64; off <<= 1) {
        int t = __shfl_up(s, off, 64);
        if (lane >= off) s += t;
    }
    if (lane == 63) wsum[wv] = s;
    __syncthreads();
    int woff = 0;
#pragma unroll
    for (int i = 0; i < 4; i++) woff += (i < wv) ? wsum[i] : 0;
    int abspos = lo + woff + (s - c);
    if (base_node + tid < N) row_ptr[base_node + tid] = abspos;
    res[tid] = abspos;
    __syncthreads();
    for (int i = lo + tid; i < hi; i += 256) {
        int val = binned[i];
        int r = atomicAdd(&res[val >> 17], 1);
        esrc[r] = val & 0x1FFFF;
    }
    if (b == 0 && tid == 0) row_ptr[N] = E;
}

// ---------------- gather: T[i](bf16) = relu(Y[i] + bias + sum_{e} Y[src[e]]) ----------------
// R8-proven exactly: one wave per node, 25K blocks, 20 VGPRs, 67% occupancy
__global__ __launch_bounds__(256) void gather_kernel(const unsigned short* __restrict__ Y,
                                                     const int* __restrict__ row_ptr,
                                                     const int* __restrict__ esrc,
                                                     const float* __restrict__ bias,
                                                     unsigned short* __restrict__ T, int N) {
    int wv = threadIdx.x >> 6, lane = threadIdx.x & 63;
    int node = blockIdx.x * 4 + wv;
    if (node >= N) return;
    float acc = bf2f(Y[(size_t)node * 64 + lane]) + bias[lane];
    int e0 = row_ptr[node], e1 = row_ptr[node + 1];
    int e = e0;
    for (; e + 8 <= e1; e += 8) {
        int s0 = esrc[e], s1 = esrc[e + 1], s2 = esrc[e + 2], s3 = esrc[e + 3];
        int s4 = esrc[e + 4], s5 = esrc[e + 5], s6 = esrc[e + 6], s7 = esrc[e + 7];
        float f0 = bf2f(Y[(size_t)s0 * 64 + lane]);
        float f1 = bf2f(Y[(size_t)s1 * 64 + lane]);
        float f2 = bf2f(Y[(size_t)s2 * 64 + lane]);
        float f3 = bf2f(Y[(size_t)s3 * 64 + lane]);
        float f4 = bf2f(Y[(size_t)s4 * 64 + lane]);
        float f5 = bf2f(Y[(size_t)s5 * 64 + lane]);
        float f6 = bf2f(Y[(size_t)s6 * 64 + lane]);
        float f7 = bf2f(Y[(size_t)s7 * 64 + lane]);
        acc += ((f0 + f1) + (f2 + f3)) + ((f4 + f5) + (f6 + f7));
    }
    for (; e < e1; e++) acc += bf2f(Y[(size_t)esrc[e] * 64 + lane]);
    T[(size_t)node * 64 + lane] = f2bf(fmaxf(acc, 0.f));
}

// stage 16 nodes x 64 feats of bf16 into f32 LDS tile
__device__ __forceinline__ void stage_bf16_tile(const unsigned short* __restrict__ src,
                                                float* __restrict__ dst, int tid) {
    const ushort4* s4 = (const ushort4*)src;
    ushort4 u = s4[tid];  // 256 threads x 4 elems = 1024
    float4* d4 = (float4*)dst;
    d4[tid] = make_float4(bf2f(u.x), bf2f(u.y), bf2f(u.z), bf2f(u.w));
}

// ---------------- fused: Y(bf16) = (relu(bn(T@W1^T + b1))) @ W2^T ----------------
__global__ __launch_bounds__(256) void fused_mlp2_kernel(
    const unsigned short* __restrict__ T, const float* __restrict__ W1,
    const float* __restrict__ b1, const float* __restrict__ g, const float* __restrict__ be,
    const float* __restrict__ m, const float* __restrict__ v, const float* __restrict__ W2,
    unsigned short* __restrict__ Y, int N) {
    __shared__ float w1lds[64 * 64];
    __shared__ float w2lds[64 * 64];
    __shared__ float tl[16 * 64];
    __shared__ float hl[16 * 64];
    int tid = threadIdx.x, wv = tid >> 6, lane = tid & 63;
    for (int j = tid; j < 4096; j += 256) {
        int o = j >> 6, k = j & 63;
        int idx = (k >> 2) * 256 + o * 4 + (k & 3);
        w1lds[idx] = W1[j];
        w2lds[idx] = W2[j];
    }
    float bias = b1[lane];
    float s = g[lane] * rsqrtf(v[lane] + BN_EPS);
    float c = be[lane] - m[lane] * s;
    __syncthreads();
    const float4* w14 = (const float4*)w1lds;
    const float4* w24 = (const float4*)w2lds;
    const float4* t4 = (const float4*)tl;
    const float4* h4 = (const float4*)hl;
    for (int nb = blockIdx.x * 16; nb < N; nb += gridDim.x * 16) {
        stage_bf16_tile(T + (size_t)nb * 64, tl, tid);
        __syncthreads();
        int r = wv * 4;
        float a0 = bias, a1 = bias, a2 = bias, a3 = bias;
#pragma unroll
        for (int kb = 0; kb < 16; kb++) {
            float4 w = w14[kb * 64 + lane];
            float4 x0 = t4[(r + 0) * 16 + kb];
            float4 x1 = t4[(r + 1) * 16 + kb];
            float4 x2 = t4[(r + 2) * 16 + kb];
            float4 x3 = t4[(r + 3) * 16 + kb];
            a0 += x0.x * w.x + x0.y * w.y + x0.z * w.z + x0.w * w.w;
            a1 += x1.x * w.x + x1.y * w.y + x1.z * w.z + x1.w * w.w;
            a2 += x2.x * w.x + x2.y * w.y + x2.z * w.z + x2.w * w.w;
            a3 += x3.x * w.x + x3.y * w.y + x3.z * w.z + x3.w * w.w;
        }
        a0 = fmaxf(a0 * s + c, 0.f);
        a1 = fmaxf(a1 * s + c, 0.f);
        a2 = fmaxf(a2 * s + c, 0.f);
        a3 = fmaxf(a3 * s + c, 0.f);
        hl[(r + 0) * 64 + lane] = a0;
        hl[(r + 1) * 64 + lane] = a1;
        hl[(r + 2) * 64 + lane] = a2;
        hl[(r + 3) * 64 + lane] = a3;
        __syncthreads();
        float o0 = 0.f, o1 = 0.f, o2 = 0.f, o3 = 0.f;
#pragma unroll
        for (int kb = 0; kb < 16; kb++) {
            float4 w = w24[kb * 64 + lane];
            float4 x0 = h4[(r + 0) * 16 + kb];
            float4 x1 = h4[(r + 1) * 16 + kb];
            float4 x2 = h4[(r + 2) * 16 + kb];
            float4 x3 = h4[(r + 3) * 16 + kb];
            o0 += x0.x * w.x + x0.y * w.y + x0.z * w.z + x0.w * w.w;
            o1 += x1.x * w.x + x1.y * w.y + x1.z * w.z + x1.w * w.w;
            o2 += x2.x * w.x + x2.y * w.y + x2.z * w.z + x2.w * w.w;
            o3 += x3.x * w.x + x3.y * w.y + x3.z * w.z + x3.w * w.w;
        }
        Y[(size_t)(nb + r + 0) * 64 + lane] = f2bf(o0);
        Y[(size_t)(nb + r + 1) * 64 + lane] = f2bf(o1);
        Y[(size_t)(nb + r + 2) * 64 + lane] = f2bf(o2);
        Y[(size_t)(nb + r + 3) * 64 + lane] = f2bf(o3);
        __syncthreads();
    }
}

// ---------------- H(bf16) = relu(bn(T@W^T + b)) ----------------
__global__ __launch_bounds__(256) void fused_mlp1_kernel(
    const unsigned short* __restrict__ T, const float* __restrict__ W,
    const float* __restrict__ b, const float* __restrict__ g, const float* __restrict__ be,
    const float* __restrict__ m, const float* __restrict__ v,
    unsigned short* __restrict__ H, int N) {
    __shared__ float wlds[64 * 64];
    __shared__ float tl[16 * 64];
    int tid = threadIdx.x, wv = tid >> 6, lane = tid & 63;
    for (int j = tid; j < 4096; j += 256) {
        int o = j >> 6, k = j & 63;
        wlds[(k >> 2) * 256 + o * 4 + (k & 3)] = W[j];
    }
    float bias = b[lane];
    float s = g[lane] * rsqrtf(v[lane] + BN_EPS);
    float c = be[lane] - m[lane] * s;
    __syncthreads();
    const float4* w4 = (const float4*)wlds;
    const float4* t4 = (const float4*)tl;
    for (int nb = blockIdx.x * 16; nb < N; nb += gridDim.x * 16) {
        stage_bf16_tile(T + (size_t)nb * 64, tl, tid);
        __syncthreads();
        int r = wv * 4;
        float a0 = bias, a1 = bias, a2 = bias, a3 = bias;
#pragma unroll
        for (int kb = 0; kb < 16; kb++) {
            float4 w = w4[kb * 64 + lane];
            float4 x0 = t4[(r + 0) * 16 + kb];
            float4 x1 = t4[(r + 1) * 16 + kb];
            float4 x2 = t4[(r + 2) * 16 + kb];
            float4 x3 = t4[(r + 3) * 16 + kb];
            a0 += x0.x * w.x + x0.y * w.y + x0.z * w.z + x0.w * w.w;
            a1 += x1.x * w.x + x1.y * w.y + x1.z * w.z + x1.w * w.w;
            a2 += x2.x * w.x + x2.y * w.y + x2.z * w.z + x2.w * w.w;
            a3 += x3.x * w.x + x3.y * w.y + x3.z * w.z + x3.w * w.w;
        }
        H[(size_t)(nb + r + 0) * 64 + lane] = f2bf(fmaxf(a0 * s + c, 0.f));
        H[(size_t)(nb + r + 1) * 64 + lane] = f2bf(fmaxf(a1 * s + c, 0.f));
        H[(size_t)(nb + r + 2) * 64 + lane] = f2bf(fmaxf(a2 * s + c, 0.f));
        H[(size_t)(nb + r + 3) * 64 + lane] = f2bf(fmaxf(a3 * s + c, 0.f));
        __syncthreads();
    }
}

// ---------------- mean pool per graph (batch is sorted) ----------------
__global__ __launch_bounds__(256) void pool_kernel(const unsigned short* __restrict__ H,
                                                   const int* __restrict__ batch,
                                                   float* __restrict__ out, int N) {
    __shared__ float part[4][64];
    int g = blockIdx.x;
    int tid = threadIdx.x, wv = tid >> 6, lane = tid & 63;
    int lo = 0, hi = N;
    while (lo < hi) { int mid = (lo + hi) >> 1; if (batch[mid] < g) lo = mid + 1; else hi = mid; }
    int start = lo;
    hi = N;
    while (lo < hi) { int mid = (lo + hi) >> 1; if (batch[mid] < g + 1) lo = mid + 1; else hi = mid; }
    int end = lo;
    float acc = 0.f;
    for (int i = start + wv; i < end; i += 4) acc += bf2f(H[(size_t)i * 64 + lane]);
    part[wv][lane] = acc;
    __syncthreads();
    if (tid < 64) {
        float sfin = part[0][tid] + part[1][tid] + part[2][tid] + part[3][tid];
        float cnt = (float)(end - start);
        out[(size_t)g * 64 + tid] = sfin / fmaxf(cnt, 1.f);
    }
}

extern "C" void kernel_launch(void* const* d_in, const int* in_sizes, int n_in,
                              void* d_out, int out_size, void* d_ws, size_t ws_size,
                              hipStream_t stream) {
    const float* x   = (const float*)d_in[0];
    const int*   ei  = (const int*)d_in[1];
    const int*   bat = (const int*)d_in[2];
    const float* W1a = (const float*)d_in[3];
    const float* b1a = (const float*)d_in[4];
    const float* W1b = (const float*)d_in[5];
    const float* b1b = (const float*)d_in[6];
    const float* g1  = (const float*)d_in[7];
    const float* be1 = (const float*)d_in[8];
    const float* m1  = (const float*)d_in[9];
    const float* v1  = (const float*)d_in[10];
    const float* W2a = (const float*)d_in[11];
    const float* b2a = (const float*)d_in[12];
    const float* W2b = (const float*)d_in[13];
    const float* b2b = (const float*)d_in[14];
    const float* g2  = (const float*)d_in[15];
    const float* be2 = (const float*)d_in[16];
    const float* m2  = (const float*)d_in[17];
    const float* v2  = (const float*)d_in[18];
    float* out = (float*)d_out;

    int N = in_sizes[0] / 128;
    int E = in_sizes[1] / 2;
    int G = out_size / 64;
    int nbuck = (N + 255) >> 8;
    int nchunk = (E + CHUNK - 1) / CHUNK;
    int grid2 = (nchunk > nbuck) ? nchunk : nbuck;

    // workspace layout
    char* ws = (char*)d_ws;
    int* done = (int*)ws;                                 // 4 (done[0]=K1, done[1]=K2)
    int* bcnt = done + 4;                                 // MAXB
    int* boff = bcnt + MAXB;                              // MAXB+4
    int* bpos = boff + MAXB + 4;                          // MAXB
    int* row_ptr = bpos + MAXB;                           // N+1 (padded)
    int* esrc = row_ptr + ((N + 2 + 3) & ~3);             // E
    int* binned = esrc + E;                               // E
    unsigned short* bufA = (unsigned short*)(binned + E); // N*64 bf16
    unsigned short* bufB = bufA + (size_t)N * 64;         // N*64 bf16

    // one memset zeroes done counters + bcnt (contiguous)
    hipMemsetAsync(done, 0, (4 + MAXB) * sizeof(int), stream);

    // K1: histogram + last-block scan + linear (x @ W1a^T -> bufA)
    k1_count_scan_linear<<<NCB + 2048, 256, 0, stream>>>(ei, E, x, W1a, bcnt, boff, bpos,
                                                         done, bufA, N, nbuck);
    // K2: bin_scatter + grid sync + bucket_csr -> row_ptr/esrc
    k2_scatter_csr<<<grid2, 256, 0, stream>>>(ei, E, bpos, binned, boff, row_ptr, esrc,
                                              done + 1, N, nbuck, nchunk);

    // layer 1 (R8-proven kernels)
    gather_kernel<<<(N + 3) / 4, 256, 0, stream>>>(bufA, row_ptr, esrc, b1a, bufB, N);
    fused_mlp2_kernel<<<2048, 256, 0, stream>>>(bufB, W1b, b1b, g1, be1, m1, v1, W2a, bufA, N);

    // layer 2
    gather_kernel<<<(N + 3) / 4, 256, 0, stream>>>(bufA, row_ptr, esrc, b2a, bufB, N);
    fused_mlp1_kernel<<<2048, 256, 0, stream>>>(bufB, W2b, b2b, g2, be2, m2, v2, bufA, N);

    // mean pool
    pool_kernel<<<G, 256, 0, stream>>>(bufA, bat, out, N);
}

// Round 11
// 503.029 us; speedup vs baseline: 2.3130x; 1.3110x over previous
//
#include <hip/hip_runtime.h>

#define BN_EPS 1e-5f
#define CHUNK 4096
#define MAXB 512   // max buckets (N up to 131072 with 256 nodes/bucket)
#define NCB 512    // count blocks in K1

// bf16 helpers (RNE pack, cheap unpack)
__device__ __forceinline__ unsigned short f2bf(float f) {
    unsigned int u = __float_as_uint(f);
    u += 0x7FFF + ((u >> 16) & 1);
    return (unsigned short)(u >> 16);
}
__device__ __forceinline__ float bf2f(unsigned short h) {
    return __uint_as_float((unsigned int)h << 16);
}

// ================= K1: bin_count (+last-block scan) fused with linear =================
// blocks [0,NCB): LDS histogram of dst>>8 -> global atomic bcnt; LAST count block
// (one fetch_add each, NO spinning) scans bcnt -> boff/bpos.
// blocks [NCB, NCB+2048): Y[n][64](bf16) = X[n][128] @ W^T (R8-proven body).
__global__ __launch_bounds__(256) void k1_count_scan_linear(
    const int* __restrict__ ei, int E,
    const float* __restrict__ X, const float* __restrict__ W,
    int* __restrict__ bcnt, int* __restrict__ boff, int* __restrict__ bpos,
    int* __restrict__ done, unsigned short* __restrict__ Y, int N, int nbuck) {
    __shared__ float lds[10240];  // 40KB union
    int tid = threadIdx.x;
    if (blockIdx.x < NCB) {
        int* h = (int*)lds;
        for (int i = tid; i < MAXB; i += 256) h[i] = 0;
        __syncthreads();
        for (int e = blockIdx.x * 256 + tid; e < E; e += NCB * 256)
            atomicAdd(&h[ei[E + e] >> 8], 1);
        __syncthreads();
        for (int b = tid; b < nbuck; b += 256)
            if (h[b]) atomicAdd(&bcnt[b], h[b]);
        __threadfence();
        __shared__ int last;
        if (tid == 0) {
            int old = __hip_atomic_fetch_add(done, 1, __ATOMIC_ACQ_REL, __HIP_MEMORY_SCOPE_AGENT);
            last = (old == NCB - 1);
        }
        __syncthreads();
        if (!last) return;
        __threadfence();
        int a0 = (2 * tid < nbuck) ? bcnt[2 * tid] : 0;
        int a1 = (2 * tid + 1 < nbuck) ? bcnt[2 * tid + 1] : 0;
        int tot = a0 + a1;
        int lane = tid & 63, wv = tid >> 6;
        int s = tot;
#pragma unroll
        for (int off = 1; off < 64; off <<= 1) {
            int t = __shfl_up(s, off, 64);
            if (lane >= off) s += t;
        }
        int* wsum = (int*)lds;
        if (lane == 63) wsum[wv] = s;
        __syncthreads();
        int woff = 0;
#pragma unroll
        for (int i = 0; i < 4; i++) woff += (i < wv) ? wsum[i] : 0;
        int excl = woff + s - tot;
        if (2 * tid < nbuck) { boff[2 * tid] = excl; bpos[2 * tid] = excl; }
        if (2 * tid + 1 < nbuck) { boff[2 * tid + 1] = excl + a0; bpos[2 * tid + 1] = excl + a0; }
        if (tid == 0) boff[nbuck] = E;
        return;
    }
    // ---- linear part ----
    int bidx = blockIdx.x - NCB;
    float* wlds = lds;          // 8192 floats
    float* xlds = lds + 8192;   // 2048 floats
    for (int j = tid; j < 64 * 128; j += 256) {
        int o = j >> 7, k = j & 127;
        wlds[(k >> 2) * 256 + o * 4 + (k & 3)] = W[j];
    }
    __syncthreads();
    const float4* w4p = (const float4*)wlds;
    const float4* x4p = (const float4*)xlds;
    int wv = tid >> 6, lane = tid & 63;
    for (int nb = bidx * 16; nb < N; nb += 2048 * 16) {
        const float4* xg = (const float4*)(X + (size_t)nb * 128);
        float4* xl = (float4*)xlds;
        for (int j = tid; j < 512; j += 256) xl[j] = xg[j];
        __syncthreads();
        int r = wv * 4;
        float a0 = 0.f, a1 = 0.f, a2 = 0.f, a3 = 0.f;
#pragma unroll 8
        for (int kb = 0; kb < 32; kb++) {
            float4 w = w4p[kb * 64 + lane];
            float4 x0 = x4p[(r + 0) * 32 + kb];
            float4 x1 = x4p[(r + 1) * 32 + kb];
            float4 x2 = x4p[(r + 2) * 32 + kb];
            float4 x3 = x4p[(r + 3) * 32 + kb];
            a0 += x0.x * w.x + x0.y * w.y + x0.z * w.z + x0.w * w.w;
            a1 += x1.x * w.x + x1.y * w.y + x1.z * w.z + x1.w * w.w;
            a2 += x2.x * w.x + x2.y * w.y + x2.z * w.z + x2.w * w.w;
            a3 += x3.x * w.x + x3.y * w.y + x3.z * w.z + x3.w * w.w;
        }
        Y[(size_t)(nb + r + 0) * 64 + lane] = f2bf(a0);
        Y[(size_t)(nb + r + 1) * 64 + lane] = f2bf(a1);
        Y[(size_t)(nb + r + 2) * 64 + lane] = f2bf(a2);
        Y[(size_t)(nb + r + 3) * 64 + lane] = f2bf(a3);
        __syncthreads();
    }
}

// ---------------- bin_scatter: R8-proven (4K chunks, 391 blocks) ----------------
__global__ __launch_bounds__(256) void bin_scatter(const int* __restrict__ ei, int E,
                                                   int* __restrict__ bpos,
                                                   int* __restrict__ binned, int nbuck) {
    __shared__ int h[MAXB];
    __shared__ int res[MAXB];
    int base = blockIdx.x * CHUNK;
    int cnt = min(CHUNK, E - base);
    int tid = threadIdx.x;
    for (int b = tid; b < nbuck; b += 256) h[b] = 0;
    __syncthreads();
    for (int k = tid; k < cnt; k += 256) {
        int d = ei[E + base + k];
        atomicAdd(&h[d >> 8], 1);
    }
    __syncthreads();
    for (int b = tid; b < nbuck; b += 256) {
        int c = h[b];
        res[b] = c ? atomicAdd(&bpos[b], c) : 0;
        h[b] = 0;  // reuse as rank counter
    }
    __syncthreads();
    for (int k = tid; k < cnt; k += 256) {
        int srcv = ei[base + k];
        int d = ei[E + base + k];
        int b = d >> 8;
        int r = atomicAdd(&h[b], 1);
        binned[res[b] + r] = ((d & 255) << 17) | srcv;  // src < 2^17
    }
}

// ---------------- bucket_csr: R8-proven (one block per 256-node bucket) ----------------
__global__ __launch_bounds__(256) void bucket_csr(const int* __restrict__ binned,
                                                  const int* __restrict__ boff,
                                                  int* __restrict__ row_ptr,
                                                  int* __restrict__ esrc, int N, int E) {
    __shared__ int ncnt[256];
    __shared__ int npos[256];
    __shared__ int wsum[4];
    int b = blockIdx.x, tid = threadIdx.x, lane = tid & 63, wv = tid >> 6;
    int lo = boff[b], hi = boff[b + 1];
    int base_node = b << 8;
    ncnt[tid] = 0;
    __syncthreads();
    for (int i = lo + tid; i < hi; i += 256)
        atomicAdd(&ncnt[binned[i] >> 17], 1);
    __syncthreads();
    int c = ncnt[tid];
    int s = c;
#pragma unroll
    for (int off = 1; off < 64; off <<= 1) {
        int t = __shfl_up(s, off, 64);
        if (lane >= off) s += t;
    }
    if (lane == 63) wsum[wv] = s;
    __syncthreads();
    int woff = 0;
#pragma unroll
    for (int i = 0; i < 4; i++) woff += (i < wv) ? wsum[i] : 0;
    int abspos = lo + woff + (s - c);
    if (base_node + tid < N) row_ptr[base_node + tid] = abspos;
    npos[tid] = abspos;
    __syncthreads();
    for (int i = lo + tid; i < hi; i += 256) {
        int val = binned[i];
        int r = atomicAdd(&npos[val >> 17], 1);
        esrc[r] = val & 0x1FFFF;
    }
    if (b == 0 && tid == 0) row_ptr[N] = E;
}

// ---------------- gather: T[i](bf16) = relu(Y[i] + bias + sum_{e} Y[src[e]]) ----------------
// R8-proven exactly: one wave per node, 25K blocks, 20 VGPRs, 67% occupancy
__global__ __launch_bounds__(256) void gather_kernel(const unsigned short* __restrict__ Y,
                                                     const int* __restrict__ row_ptr,
                                                     const int* __restrict__ esrc,
                                                     const float* __restrict__ bias,
                                                     unsigned short* __restrict__ T, int N) {
    int wv = threadIdx.x >> 6, lane = threadIdx.x & 63;
    int node = blockIdx.x * 4 + wv;
    if (node >= N) return;
    float acc = bf2f(Y[(size_t)node * 64 + lane]) + bias[lane];
    int e0 = row_ptr[node], e1 = row_ptr[node + 1];
    int e = e0;
    for (; e + 8 <= e1; e += 8) {
        int s0 = esrc[e], s1 = esrc[e + 1], s2 = esrc[e + 2], s3 = esrc[e + 3];
        int s4 = esrc[e + 4], s5 = esrc[e + 5], s6 = esrc[e + 6], s7 = esrc[e + 7];
        float f0 = bf2f(Y[(size_t)s0 * 64 + lane]);
        float f1 = bf2f(Y[(size_t)s1 * 64 + lane]);
        float f2 = bf2f(Y[(size_t)s2 * 64 + lane]);
        float f3 = bf2f(Y[(size_t)s3 * 64 + lane]);
        float f4 = bf2f(Y[(size_t)s4 * 64 + lane]);
        float f5 = bf2f(Y[(size_t)s5 * 64 + lane]);
        float f6 = bf2f(Y[(size_t)s6 * 64 + lane]);
        float f7 = bf2f(Y[(size_t)s7 * 64 + lane]);
        acc += ((f0 + f1) + (f2 + f3)) + ((f4 + f5) + (f6 + f7));
    }
    for (; e < e1; e++) acc += bf2f(Y[(size_t)esrc[e] * 64 + lane]);
    T[(size_t)node * 64 + lane] = f2bf(fmaxf(acc, 0.f));
}

// stage 16 nodes x 64 feats of bf16 into f32 LDS tile
__device__ __forceinline__ void stage_bf16_tile(const unsigned short* __restrict__ src,
                                                float* __restrict__ dst, int tid) {
    const ushort4* s4 = (const ushort4*)src;
    ushort4 u = s4[tid];  // 256 threads x 4 elems = 1024
    float4* d4 = (float4*)dst;
    d4[tid] = make_float4(bf2f(u.x), bf2f(u.y), bf2f(u.z), bf2f(u.w));
}

// ---------------- fused: Y(bf16) = (relu(bn(T@W1^T + b1))) @ W2^T ----------------
__global__ __launch_bounds__(256) void fused_mlp2_kernel(
    const unsigned short* __restrict__ T, const float* __restrict__ W1,
    const float* __restrict__ b1, const float* __restrict__ g, const float* __restrict__ be,
    const float* __restrict__ m, const float* __restrict__ v, const float* __restrict__ W2,
    unsigned short* __restrict__ Y, int N) {
    __shared__ float w1lds[64 * 64];
    __shared__ float w2lds[64 * 64];
    __shared__ float tl[16 * 64];
    __shared__ float hl[16 * 64];
    int tid = threadIdx.x, wv = tid >> 6, lane = tid & 63;
    for (int j = tid; j < 4096; j += 256) {
        int o = j >> 6, k = j & 63;
        int idx = (k >> 2) * 256 + o * 4 + (k & 3);
        w1lds[idx] = W1[j];
        w2lds[idx] = W2[j];
    }
    float bias = b1[lane];
    float s = g[lane] * rsqrtf(v[lane] + BN_EPS);
    float c = be[lane] - m[lane] * s;
    __syncthreads();
    const float4* w14 = (const float4*)w1lds;
    const float4* w24 = (const float4*)w2lds;
    const float4* t4 = (const float4*)tl;
    const float4* h4 = (const float4*)hl;
    for (int nb = blockIdx.x * 16; nb < N; nb += gridDim.x * 16) {
        stage_bf16_tile(T + (size_t)nb * 64, tl, tid);
        __syncthreads();
        int r = wv * 4;
        float a0 = bias, a1 = bias, a2 = bias, a3 = bias;
#pragma unroll
        for (int kb = 0; kb < 16; kb++) {
            float4 w = w14[kb * 64 + lane];
            float4 x0 = t4[(r + 0) * 16 + kb];
            float4 x1 = t4[(r + 1) * 16 + kb];
            float4 x2 = t4[(r + 2) * 16 + kb];
            float4 x3 = t4[(r + 3) * 16 + kb];
            a0 += x0.x * w.x + x0.y * w.y + x0.z * w.z + x0.w * w.w;
            a1 += x1.x * w.x + x1.y * w.y + x1.z * w.z + x1.w * w.w;
            a2 += x2.x * w.x + x2.y * w.y + x2.z * w.z + x2.w * w.w;
            a3 += x3.x * w.x + x3.y * w.y + x3.z * w.z + x3.w * w.w;
        }
        a0 = fmaxf(a0 * s + c, 0.f);
        a1 = fmaxf(a1 * s + c, 0.f);
        a2 = fmaxf(a2 * s + c, 0.f);
        a3 = fmaxf(a3 * s + c, 0.f);
        hl[(r + 0) * 64 + lane] = a0;
        hl[(r + 1) * 64 + lane] = a1;
        hl[(r + 2) * 64 + lane] = a2;
        hl[(r + 3) * 64 + lane] = a3;
        __syncthreads();
        float o0 = 0.f, o1 = 0.f, o2 = 0.f, o3 = 0.f;
#pragma unroll
        for (int kb = 0; kb < 16; kb++) {
            float4 w = w24[kb * 64 + lane];
            float4 x0 = h4[(r + 0) * 16 + kb];
            float4 x1 = h4[(r + 1) * 16 + kb];
            float4 x2 = h4[(r + 2) * 16 + kb];
            float4 x3 = h4[(r + 3) * 16 + kb];
            o0 += x0.x * w.x + x0.y * w.y + x0.z * w.z + x0.w * w.w;
            o1 += x1.x * w.x + x1.y * w.y + x1.z * w.z + x1.w * w.w;
            o2 += x2.x * w.x + x2.y * w.y + x2.z * w.z + x2.w * w.w;
            o3 += x3.x * w.x + x3.y * w.y + x3.z * w.z + x3.w * w.w;
        }
        Y[(size_t)(nb + r + 0) * 64 + lane] = f2bf(o0);
        Y[(size_t)(nb + r + 1) * 64 + lane] = f2bf(o1);
        Y[(size_t)(nb + r + 2) * 64 + lane] = f2bf(o2);
        Y[(size_t)(nb + r + 3) * 64 + lane] = f2bf(o3);
        __syncthreads();
    }
}

// ---------------- H(bf16) = relu(bn(T@W^T + b)) ----------------
__global__ __launch_bounds__(256) void fused_mlp1_kernel(
    const unsigned short* __restrict__ T, const float* __restrict__ W,
    const float* __restrict__ b, const float* __restrict__ g, const float* __restrict__ be,
    const float* __restrict__ m, const float* __restrict__ v,
    unsigned short* __restrict__ H, int N) {
    __shared__ float wlds[64 * 64];
    __shared__ float tl[16 * 64];
    int tid = threadIdx.x, wv = tid >> 6, lane = tid & 63;
    for (int j = tid; j < 4096; j += 256) {
        int o = j >> 6, k = j & 63;
        wlds[(k >> 2) * 256 + o * 4 + (k & 3)] = W[j];
    }
    float bias = b[lane];
    float s = g[lane] * rsqrtf(v[lane] + BN_EPS);
    float c = be[lane] - m[lane] * s;
    __syncthreads();
    const float4* w4 = (const float4*)wlds;
    const float4* t4 = (const float4*)tl;
    for (int nb = blockIdx.x * 16; nb < N; nb += gridDim.x * 16) {
        stage_bf16_tile(T + (size_t)nb * 64, tl, tid);
        __syncthreads();
        int r = wv * 4;
        float a0 = bias, a1 = bias, a2 = bias, a3 = bias;
#pragma unroll
        for (int kb = 0; kb < 16; kb++) {
            float4 w = w4[kb * 64 + lane];
            float4 x0 = t4[(r + 0) * 16 + kb];
            float4 x1 = t4[(r + 1) * 16 + kb];
            float4 x2 = t4[(r + 2) * 16 + kb];
            float4 x3 = t4[(r + 3) * 16 + kb];
            a0 += x0.x * w.x + x0.y * w.y + x0.z * w.z + x0.w * w.w;
            a1 += x1.x * w.x + x1.y * w.y + x1.z * w.z + x1.w * w.w;
            a2 += x2.x * w.x + x2.y * w.y + x2.z * w.z + x2.w * w.w;
            a3 += x3.x * w.x + x3.y * w.y + x3.z * w.z + x3.w * w.w;
        }
        H[(size_t)(nb + r + 0) * 64 + lane] = f2bf(fmaxf(a0 * s + c, 0.f));
        H[(size_t)(nb + r + 1) * 64 + lane] = f2bf(fmaxf(a1 * s + c, 0.f));
        H[(size_t)(nb + r + 2) * 64 + lane] = f2bf(fmaxf(a2 * s + c, 0.f));
        H[(size_t)(nb + r + 3) * 64 + lane] = f2bf(fmaxf(a3 * s + c, 0.f));
        __syncthreads();
    }
}

// ---------------- mean pool per graph (batch is sorted) ----------------
__global__ __launch_bounds__(256) void pool_kernel(const unsigned short* __restrict__ H,
                                                   const int* __restrict__ batch,
                                                   float* __restrict__ out, int N) {
    __shared__ float part[4][64];
    int g = blockIdx.x;
    int tid = threadIdx.x, wv = tid >> 6, lane = tid & 63;
    int lo = 0, hi = N;
    while (lo < hi) { int mid = (lo + hi) >> 1; if (batch[mid] < g) lo = mid + 1; else hi = mid; }
    int start = lo;
    hi = N;
    while (lo < hi) { int mid = (lo + hi) >> 1; if (batch[mid] < g + 1) lo = mid + 1; else hi = mid; }
    int end = lo;
    float acc = 0.f;
    for (int i = start + wv; i < end; i += 4) acc += bf2f(H[(size_t)i * 64 + lane]);
    part[wv][lane] = acc;
    __syncthreads();
    if (tid < 64) {
        float sfin = part[0][tid] + part[1][tid] + part[2][tid] + part[3][tid];
        float cnt = (float)(end - start);
        out[(size_t)g * 64 + tid] = sfin / fmaxf(cnt, 1.f);
    }
}

extern "C" void kernel_launch(void* const* d_in, const int* in_sizes, int n_in,
                              void* d_out, int out_size, void* d_ws, size_t ws_size,
                              hipStream_t stream) {
    const float* x   = (const float*)d_in[0];
    const int*   ei  = (const int*)d_in[1];
    const int*   bat = (const int*)d_in[2];
    const float* W1a = (const float*)d_in[3];
    const float* b1a = (const float*)d_in[4];
    const float* W1b = (const float*)d_in[5];
    const float* b1b = (const float*)d_in[6];
    const float* g1  = (const float*)d_in[7];
    const float* be1 = (const float*)d_in[8];
    const float* m1  = (const float*)d_in[9];
    const float* v1  = (const float*)d_in[10];
    const float* W2a = (const float*)d_in[11];
    const float* b2a = (const float*)d_in[12];
    const float* W2b = (const float*)d_in[13];
    const float* b2b = (const float*)d_in[14];
    const float* g2  = (const float*)d_in[15];
    const float* be2 = (const float*)d_in[16];
    const float* m2  = (const float*)d_in[17];
    const float* v2  = (const float*)d_in[18];
    float* out = (float*)d_out;

    int N = in_sizes[0] / 128;
    int E = in_sizes[1] / 2;
    int G = out_size / 64;
    int nbuck = (N + 255) >> 8;
    int nchunk = (E + CHUNK - 1) / CHUNK;

    // workspace layout
    char* ws = (char*)d_ws;
    int* done = (int*)ws;                                 // 4
    int* bcnt = done + 4;                                 // MAXB
    int* boff = bcnt + MAXB;                              // MAXB+4
    int* bpos = boff + MAXB + 4;                          // MAXB
    int* row_ptr = bpos + MAXB;                           // N+1 (padded)
    int* esrc = row_ptr + ((N + 2 + 3) & ~3);             // E
    int* binned = esrc + E;                               // E
    unsigned short* bufA = (unsigned short*)(binned + E); // N*64 bf16
    unsigned short* bufB = bufA + (size_t)N * 64;         // N*64 bf16

    // one memset zeroes done counter + bcnt (contiguous)
    hipMemsetAsync(done, 0, (4 + MAXB) * sizeof(int), stream);

    // K1: histogram + last-block scan + linear (x @ W1a^T -> bufA)
    k1_count_scan_linear<<<NCB + 2048, 256, 0, stream>>>(ei, E, x, W1a, bcnt, boff, bpos,
                                                         done, bufA, N, nbuck);
    // CSR: separate dispatches (R8-proven; no spin barrier)
    bin_scatter<<<nchunk, 256, 0, stream>>>(ei, E, bpos, binned, nbuck);
    bucket_csr<<<nbuck, 256, 0, stream>>>(binned, boff, row_ptr, esrc, N, E);

    // layer 1
    gather_kernel<<<(N + 3) / 4, 256, 0, stream>>>(bufA, row_ptr, esrc, b1a, bufB, N);
    fused_mlp2_kernel<<<2048, 256, 0, stream>>>(bufB, W1b, b1b, g1, be1, m1, v1, W2a, bufA, N);

    // layer 2
    gather_kernel<<<(N + 3) / 4, 256, 0, stream>>>(bufA, row_ptr, esrc, b2a, bufB, N);
    fused_mlp1_kernel<<<2048, 256, 0, stream>>>(bufB, W2b, b2b, g2, be2, m2, v2, bufA, N);

    // mean pool
    pool_kernel<<<G, 256, 0, stream>>>(bufA, bat, out, N);
}

// Round 12
// 482.786 us; speedup vs baseline: 2.4100x; 1.0419x over previous
//
#include <hip/hip_runtime.h>

#define BN_EPS 1e-5f
#define CHUNK 4096
#define MAXB 512   // max buckets (N up to 131072 with 256 nodes/bucket)
#define NCB 512    // count blocks

// bf16 helpers (RNE pack, cheap unpack)
__device__ __forceinline__ unsigned short f2bf(float f) {
    unsigned int u = __float_as_uint(f);
    u += 0x7FFF + ((u >> 16) & 1);
    return (unsigned short)(u >> 16);
}
__device__ __forceinline__ float bf2f(unsigned short h) {
    return __uint_as_float((unsigned int)h << 16);
}

// ---------------- count_scan: bin_count + last-finisher scan (2KB LDS, no payload) ----------------
__global__ __launch_bounds__(256) void count_scan(const int* __restrict__ ei, int E,
                                                  int* __restrict__ bcnt,
                                                  int* __restrict__ boff,
                                                  int* __restrict__ bpos,
                                                  int* __restrict__ done, int nbuck) {
    __shared__ int h[MAXB];
    __shared__ int wsum[4];
    __shared__ int last;
    int tid = threadIdx.x;
    for (int i = tid; i < MAXB; i += 256) h[i] = 0;
    __syncthreads();
    for (int e = blockIdx.x * 256 + tid; e < E; e += NCB * 256)
        atomicAdd(&h[ei[E + e] >> 8], 1);
    __syncthreads();
    for (int b = tid; b < nbuck; b += 256)
        if (h[b]) atomicAdd(&bcnt[b], h[b]);
    __threadfence();
    if (tid == 0) {
        int old = __hip_atomic_fetch_add(done, 1, __ATOMIC_ACQ_REL, __HIP_MEMORY_SCOPE_AGENT);
        last = (old == NCB - 1);
    }
    __syncthreads();
    if (!last) return;
    __threadfence();
    // exclusive scan of bcnt[0..nbuck), 2 entries/thread
    int a0 = (2 * tid < nbuck) ? bcnt[2 * tid] : 0;
    int a1 = (2 * tid + 1 < nbuck) ? bcnt[2 * tid + 1] : 0;
    int tot = a0 + a1;
    int lane = tid & 63, wv = tid >> 6;
    int s = tot;
#pragma unroll
    for (int off = 1; off < 64; off <<= 1) {
        int t = __shfl_up(s, off, 64);
        if (lane >= off) s += t;
    }
    if (lane == 63) wsum[wv] = s;
    __syncthreads();
    int woff = 0;
#pragma unroll
    for (int i = 0; i < 4; i++) woff += (i < wv) ? wsum[i] : 0;
    int excl = woff + s - tot;
    if (2 * tid < nbuck) { boff[2 * tid] = excl; bpos[2 * tid] = excl; }
    if (2 * tid + 1 < nbuck) { boff[2 * tid + 1] = excl + a0; bpos[2 * tid + 1] = excl + a0; }
    if (tid == 0) boff[nbuck] = E;
}

// ---------------- bin_scatter: R8-proven (4K chunks, 391 blocks) ----------------
__global__ __launch_bounds__(256) void bin_scatter(const int* __restrict__ ei, int E,
                                                   int* __restrict__ bpos,
                                                   int* __restrict__ binned, int nbuck) {
    __shared__ int h[MAXB];
    __shared__ int res[MAXB];
    int base = blockIdx.x * CHUNK;
    int cnt = min(CHUNK, E - base);
    int tid = threadIdx.x;
    for (int b = tid; b < nbuck; b += 256) h[b] = 0;
    __syncthreads();
    for (int k = tid; k < cnt; k += 256) {
        int d = ei[E + base + k];
        atomicAdd(&h[d >> 8], 1);
    }
    __syncthreads();
    for (int b = tid; b < nbuck; b += 256) {
        int c = h[b];
        res[b] = c ? atomicAdd(&bpos[b], c) : 0;
        h[b] = 0;  // reuse as rank counter
    }
    __syncthreads();
    for (int k = tid; k < cnt; k += 256) {
        int srcv = ei[base + k];
        int d = ei[E + base + k];
        int b = d >> 8;
        int r = atomicAdd(&h[b], 1);
        binned[res[b] + r] = ((d & 255) << 17) | srcv;  // src < 2^17
    }
}

// ---------------- bucket_csr: R8-proven (one block per 256-node bucket) ----------------
__global__ __launch_bounds__(256) void bucket_csr(const int* __restrict__ binned,
                                                  const int* __restrict__ boff,
                                                  int* __restrict__ row_ptr,
                                                  int* __restrict__ esrc, int N, int E) {
    __shared__ int ncnt[256];
    __shared__ int npos[256];
    __shared__ int wsum[4];
    int b = blockIdx.x, tid = threadIdx.x, lane = tid & 63, wv = tid >> 6;
    int lo = boff[b], hi = boff[b + 1];
    int base_node = b << 8;
    ncnt[tid] = 0;
    __syncthreads();
    for (int i = lo + tid; i < hi; i += 256)
        atomicAdd(&ncnt[binned[i] >> 17], 1);
    __syncthreads();
    int c = ncnt[tid];
    int s = c;
#pragma unroll
    for (int off = 1; off < 64; off <<= 1) {
        int t = __shfl_up(s, off, 64);
        if (lane >= off) s += t;
    }
    if (lane == 63) wsum[wv] = s;
    __syncthreads();
    int woff = 0;
#pragma unroll
    for (int i = 0; i < 4; i++) woff += (i < wv) ? wsum[i] : 0;
    int abspos = lo + woff + (s - c);
    if (base_node + tid < N) row_ptr[base_node + tid] = abspos;
    npos[tid] = abspos;
    __syncthreads();
    for (int i = lo + tid; i < hi; i += 256) {
        int val = binned[i];
        int r = atomicAdd(&npos[val >> 17], 1);
        esrc[r] = val & 0x1FFFF;
    }
    if (b == 0 && tid == 0) row_ptr[N] = E;
}

// ---------------- dense: Y[n][64](bf16) = X[n][K](f32) @ W[64][K]^T (R8-proven) ----------------
template <int K>
__global__ __launch_bounds__(256) void linear_kernel(const float* __restrict__ X,
                                                     const float* __restrict__ W,
                                                     unsigned short* __restrict__ Y, int N) {
    __shared__ float wlds[K * 64];
    __shared__ float xlds[16 * K];
    int tid = threadIdx.x;
    for (int j = tid; j < 64 * K; j += 256) {
        int o = j / K, k = j % K;
        wlds[(k >> 2) * 256 + o * 4 + (k & 3)] = W[j];
    }
    __syncthreads();
    const float4* w4p = (const float4*)wlds;
    const float4* x4p = (const float4*)xlds;
    int wv = tid >> 6, lane = tid & 63;
    for (int nb = blockIdx.x * 16; nb < N; nb += gridDim.x * 16) {
        const float4* xg = (const float4*)(X + (size_t)nb * K);
        float4* xl = (float4*)xlds;
        for (int j = tid; j < 16 * K / 4; j += 256) xl[j] = xg[j];
        __syncthreads();
        int r = wv * 4;
        float a0 = 0.f, a1 = 0.f, a2 = 0.f, a3 = 0.f;
#pragma unroll 8
        for (int kb = 0; kb < K / 4; kb++) {
            float4 w = w4p[kb * 64 + lane];
            float4 x0 = x4p[(r + 0) * (K / 4) + kb];
            float4 x1 = x4p[(r + 1) * (K / 4) + kb];
            float4 x2 = x4p[(r + 2) * (K / 4) + kb];
            float4 x3 = x4p[(r + 3) * (K / 4) + kb];
            a0 += x0.x * w.x + x0.y * w.y + x0.z * w.z + x0.w * w.w;
            a1 += x1.x * w.x + x1.y * w.y + x1.z * w.z + x1.w * w.w;
            a2 += x2.x * w.x + x2.y * w.y + x2.z * w.z + x2.w * w.w;
            a3 += x3.x * w.x + x3.y * w.y + x3.z * w.z + x3.w * w.w;
        }
        Y[(size_t)(nb + r + 0) * 64 + lane] = f2bf(a0);
        Y[(size_t)(nb + r + 1) * 64 + lane] = f2bf(a1);
        Y[(size_t)(nb + r + 2) * 64 + lane] = f2bf(a2);
        Y[(size_t)(nb + r + 3) * 64 + lane] = f2bf(a3);
        __syncthreads();
    }
}

// ---------------- gather: T[i](bf16) = relu(Y[i] + bias + sum_{e} Y[src[e]]) ----------------
// R8-proven exactly: one wave per node, 25K blocks, 20 VGPRs, 67% occupancy
__global__ __launch_bounds__(256) void gather_kernel(const unsigned short* __restrict__ Y,
                                                     const int* __restrict__ row_ptr,
                                                     const int* __restrict__ esrc,
                                                     const float* __restrict__ bias,
                                                     unsigned short* __restrict__ T, int N) {
    int wv = threadIdx.x >> 6, lane = threadIdx.x & 63;
    int node = blockIdx.x * 4 + wv;
    if (node >= N) return;
    float acc = bf2f(Y[(size_t)node * 64 + lane]) + bias[lane];
    int e0 = row_ptr[node], e1 = row_ptr[node + 1];
    int e = e0;
    for (; e + 8 <= e1; e += 8) {
        int s0 = esrc[e], s1 = esrc[e + 1], s2 = esrc[e + 2], s3 = esrc[e + 3];
        int s4 = esrc[e + 4], s5 = esrc[e + 5], s6 = esrc[e + 6], s7 = esrc[e + 7];
        float f0 = bf2f(Y[(size_t)s0 * 64 + lane]);
        float f1 = bf2f(Y[(size_t)s1 * 64 + lane]);
        float f2 = bf2f(Y[(size_t)s2 * 64 + lane]);
        float f3 = bf2f(Y[(size_t)s3 * 64 + lane]);
        float f4 = bf2f(Y[(size_t)s4 * 64 + lane]);
        float f5 = bf2f(Y[(size_t)s5 * 64 + lane]);
        float f6 = bf2f(Y[(size_t)s6 * 64 + lane]);
        float f7 = bf2f(Y[(size_t)s7 * 64 + lane]);
        acc += ((f0 + f1) + (f2 + f3)) + ((f4 + f5) + (f6 + f7));
    }
    for (; e < e1; e++) acc += bf2f(Y[(size_t)esrc[e] * 64 + lane]);
    T[(size_t)node * 64 + lane] = f2bf(fmaxf(acc, 0.f));
}

// stage 16 nodes x 64 feats of bf16 into f32 LDS tile
__device__ __forceinline__ void stage_bf16_tile(const unsigned short* __restrict__ src,
                                                float* __restrict__ dst, int tid) {
    const ushort4* s4 = (const ushort4*)src;
    ushort4 u = s4[tid];  // 256 threads x 4 elems = 1024
    float4* d4 = (float4*)dst;
    d4[tid] = make_float4(bf2f(u.x), bf2f(u.y), bf2f(u.z), bf2f(u.w));
}

// ---------------- fused: Y(bf16) = (relu(bn(T@W1^T + b1))) @ W2^T ----------------
__global__ __launch_bounds__(256) void fused_mlp2_kernel(
    const unsigned short* __restrict__ T, const float* __restrict__ W1,
    const float* __restrict__ b1, const float* __restrict__ g, const float* __restrict__ be,
    const float* __restrict__ m, const float* __restrict__ v, const float* __restrict__ W2,
    unsigned short* __restrict__ Y, int N) {
    __shared__ float w1lds[64 * 64];
    __shared__ float w2lds[64 * 64];
    __shared__ float tl[16 * 64];
    __shared__ float hl[16 * 64];
    int tid = threadIdx.x, wv = tid >> 6, lane = tid & 63;
    for (int j = tid; j < 4096; j += 256) {
        int o = j >> 6, k = j & 63;
        int idx = (k >> 2) * 256 + o * 4 + (k & 3);
        w1lds[idx] = W1[j];
        w2lds[idx] = W2[j];
    }
    float bias = b1[lane];
    float s = g[lane] * rsqrtf(v[lane] + BN_EPS);
    float c = be[lane] - m[lane] * s;
    __syncthreads();
    const float4* w14 = (const float4*)w1lds;
    const float4* w24 = (const float4*)w2lds;
    const float4* t4 = (const float4*)tl;
    const float4* h4 = (const float4*)hl;
    for (int nb = blockIdx.x * 16; nb < N; nb += gridDim.x * 16) {
        stage_bf16_tile(T + (size_t)nb * 64, tl, tid);
        __syncthreads();
        int r = wv * 4;
        float a0 = bias, a1 = bias, a2 = bias, a3 = bias;
#pragma unroll
        for (int kb = 0; kb < 16; kb++) {
            float4 w = w14[kb * 64 + lane];
            float4 x0 = t4[(r + 0) * 16 + kb];
            float4 x1 = t4[(r + 1) * 16 + kb];
            float4 x2 = t4[(r + 2) * 16 + kb];
            float4 x3 = t4[(r + 3) * 16 + kb];
            a0 += x0.x * w.x + x0.y * w.y + x0.z * w.z + x0.w * w.w;
            a1 += x1.x * w.x + x1.y * w.y + x1.z * w.z + x1.w * w.w;
            a2 += x2.x * w.x + x2.y * w.y + x2.z * w.z + x2.w * w.w;
            a3 += x3.x * w.x + x3.y * w.y + x3.z * w.z + x3.w * w.w;
        }
        a0 = fmaxf(a0 * s + c, 0.f);
        a1 = fmaxf(a1 * s + c, 0.f);
        a2 = fmaxf(a2 * s + c, 0.f);
        a3 = fmaxf(a3 * s + c, 0.f);
        hl[(r + 0) * 64 + lane] = a0;
        hl[(r + 1) * 64 + lane] = a1;
        hl[(r + 2) * 64 + lane] = a2;
        hl[(r + 3) * 64 + lane] = a3;
        __syncthreads();
        float o0 = 0.f, o1 = 0.f, o2 = 0.f, o3 = 0.f;
#pragma unroll
        for (int kb = 0; kb < 16; kb++) {
            float4 w = w24[kb * 64 + lane];
            float4 x0 = h4[(r + 0) * 16 + kb];
            float4 x1 = h4[(r + 1) * 16 + kb];
            float4 x2 = h4[(r + 2) * 16 + kb];
            float4 x3 = h4[(r + 3) * 16 + kb];
            o0 += x0.x * w.x + x0.y * w.y + x0.z * w.z + x0.w * w.w;
            o1 += x1.x * w.x + x1.y * w.y + x1.z * w.z + x1.w * w.w;
            o2 += x2.x * w.x + x2.y * w.y + x2.z * w.z + x2.w * w.w;
            o3 += x3.x * w.x + x3.y * w.y + x3.z * w.z + x3.w * w.w;
        }
        Y[(size_t)(nb + r + 0) * 64 + lane] = f2bf(o0);
        Y[(size_t)(nb + r + 1) * 64 + lane] = f2bf(o1);
        Y[(size_t)(nb + r + 2) * 64 + lane] = f2bf(o2);
        Y[(size_t)(nb + r + 3) * 64 + lane] = f2bf(o3);
        __syncthreads();
    }
}

// ---------------- H(bf16) = relu(bn(T@W^T + b)) ----------------
__global__ __launch_bounds__(256) void fused_mlp1_kernel(
    const unsigned short* __restrict__ T, const float* __restrict__ W,
    const float* __restrict__ b, const float* __restrict__ g, const float* __restrict__ be,
    const float* __restrict__ m, const float* __restrict__ v,
    unsigned short* __restrict__ H, int N) {
    __shared__ float wlds[64 * 64];
    __shared__ float tl[16 * 64];
    int tid = threadIdx.x, wv = tid >> 6, lane = tid & 63;
    for (int j = tid; j < 4096; j += 256) {
        int o = j >> 6, k = j & 63;
        wlds[(k >> 2) * 256 + o * 4 + (k & 3)] = W[j];
    }
    float bias = b[lane];
    float s = g[lane] * rsqrtf(v[lane] + BN_EPS);
    float c = be[lane] - m[lane] * s;
    __syncthreads();
    const float4* w4 = (const float4*)wlds;
    const float4* t4 = (const float4*)tl;
    for (int nb = blockIdx.x * 16; nb < N; nb += gridDim.x * 16) {
        stage_bf16_tile(T + (size_t)nb * 64, tl, tid);
        __syncthreads();
        int r = wv * 4;
        float a0 = bias, a1 = bias, a2 = bias, a3 = bias;
#pragma unroll
        for (int kb = 0; kb < 16; kb++) {
            float4 w = w4[kb * 64 + lane];
            float4 x0 = t4[(r + 0) * 16 + kb];
            float4 x1 = t4[(r + 1) * 16 + kb];
            float4 x2 = t4[(r + 2) * 16 + kb];
            float4 x3 = t4[(r + 3) * 16 + kb];
            a0 += x0.x * w.x + x0.y * w.y + x0.z * w.z + x0.w * w.w;
            a1 += x1.x * w.x + x1.y * w.y + x1.z * w.z + x1.w * w.w;
            a2 += x2.x * w.x + x2.y * w.y + x2.z * w.z + x2.w * w.w;
            a3 += x3.x * w.x + x3.y * w.y + x3.z * w.z + x3.w * w.w;
        }
        H[(size_t)(nb + r + 0) * 64 + lane] = f2bf(fmaxf(a0 * s + c, 0.f));
        H[(size_t)(nb + r + 1) * 64 + lane] = f2bf(fmaxf(a1 * s + c, 0.f));
        H[(size_t)(nb + r + 2) * 64 + lane] = f2bf(fmaxf(a2 * s + c, 0.f));
        H[(size_t)(nb + r + 3) * 64 + lane] = f2bf(fmaxf(a3 * s + c, 0.f));
        __syncthreads();
    }
}

// ---------------- mean pool per graph (batch is sorted) ----------------
__global__ __launch_bounds__(256) void pool_kernel(const unsigned short* __restrict__ H,
                                                   const int* __restrict__ batch,
                                                   float* __restrict__ out, int N) {
    __shared__ float part[4][64];
    int g = blockIdx.x;
    int tid = threadIdx.x, wv = tid >> 6, lane = tid & 63;
    int lo = 0, hi = N;
    while (lo < hi) { int mid = (lo + hi) >> 1; if (batch[mid] < g) lo = mid + 1; else hi = mid; }
    int start = lo;
    hi = N;
    while (lo < hi) { int mid = (lo + hi) >> 1; if (batch[mid] < g + 1) lo = mid + 1; else hi = mid; }
    int end = lo;
    float acc = 0.f;
    for (int i = start + wv; i < end; i += 4) acc += bf2f(H[(size_t)i * 64 + lane]);
    part[wv][lane] = acc;
    __syncthreads();
    if (tid < 64) {
        float sfin = part[0][tid] + part[1][tid] + part[2][tid] + part[3][tid];
        float cnt = (float)(end - start);
        out[(size_t)g * 64 + tid] = sfin / fmaxf(cnt, 1.f);
    }
}

extern "C" void kernel_launch(void* const* d_in, const int* in_sizes, int n_in,
                              void* d_out, int out_size, void* d_ws, size_t ws_size,
                              hipStream_t stream) {
    const float* x   = (const float*)d_in[0];
    const int*   ei  = (const int*)d_in[1];
    const int*   bat = (const int*)d_in[2];
    const float* W1a = (const float*)d_in[3];
    const float* b1a = (const float*)d_in[4];
    const float* W1b = (const float*)d_in[5];
    const float* b1b = (const float*)d_in[6];
    const float* g1  = (const float*)d_in[7];
    const float* be1 = (const float*)d_in[8];
    const float* m1  = (const float*)d_in[9];
    const float* v1  = (const float*)d_in[10];
    const float* W2a = (const float*)d_in[11];
    const float* b2a = (const float*)d_in[12];
    const float* W2b = (const float*)d_in[13];
    const float* b2b = (const float*)d_in[14];
    const float* g2  = (const float*)d_in[15];
    const float* be2 = (const float*)d_in[16];
    const float* m2  = (const float*)d_in[17];
    const float* v2  = (const float*)d_in[18];
    float* out = (float*)d_out;

    int N = in_sizes[0] / 128;
    int E = in_sizes[1] / 2;
    int G = out_size / 64;
    int nbuck = (N + 255) >> 8;
    int nchunk = (E + CHUNK - 1) / CHUNK;

    // workspace layout
    char* ws = (char*)d_ws;
    int* done = (int*)ws;                                 // 4
    int* bcnt = done + 4;                                 // MAXB
    int* boff = bcnt + MAXB;                              // MAXB+4
    int* bpos = boff + MAXB + 4;                          // MAXB
    int* row_ptr = bpos + MAXB;                           // N+1 (padded)
    int* esrc = row_ptr + ((N + 2 + 3) & ~3);             // E
    int* binned = esrc + E;                               // E
    unsigned short* bufA = (unsigned short*)(binned + E); // N*64 bf16
    unsigned short* bufB = bufA + (size_t)N * 64;         // N*64 bf16

    // one memset zeroes done counter + bcnt (contiguous)
    hipMemsetAsync(done, 0, (4 + MAXB) * sizeof(int), stream);

    // CSR build: count+scan fused (last-finisher, 2KB LDS), then scatter, then csr
    count_scan<<<NCB, 256, 0, stream>>>(ei, E, bcnt, boff, bpos, done, nbuck);
    bin_scatter<<<nchunk, 256, 0, stream>>>(ei, E, bpos, binned, nbuck);
    bucket_csr<<<nbuck, 256, 0, stream>>>(binned, boff, row_ptr, esrc, N, E);

    // layer 1
    linear_kernel<128><<<2048, 256, 0, stream>>>(x, W1a, bufA, N);
    gather_kernel<<<(N + 3) / 4, 256, 0, stream>>>(bufA, row_ptr, esrc, b1a, bufB, N);
    fused_mlp2_kernel<<<2048, 256, 0, stream>>>(bufB, W1b, b1b, g1, be1, m1, v1, W2a, bufA, N);

    // layer 2
    gather_kernel<<<(N + 3) / 4, 256, 0, stream>>>(bufA, row_ptr, esrc, b2a, bufB, N);
    fused_mlp1_kernel<<<2048, 256, 0, stream>>>(bufB, W2b, b2b, g2, be2, m2, v2, bufA, N);

    // mean pool
    pool_kernel<<<G, 256, 0, stream>>>(bufA, bat, out, N);
}

// Round 13
// 451.594 us; speedup vs baseline: 2.5764x; 1.0691x over previous
//
#include <hip/hip_runtime.h>

#define BN_EPS 1e-5f
#define CHUNK 4096
#define MAXB 512  // max buckets (N up to 131072 with 256 nodes/bucket)

// bf16 helpers (RNE pack, cheap unpack)
__device__ __forceinline__ unsigned short f2bf(float f) {
    unsigned int u = __float_as_uint(f);
    u += 0x7FFF + ((u >> 16) & 1);
    return (unsigned short)(u >> 16);
}
__device__ __forceinline__ float bf2f(unsigned short h) {
    return __uint_as_float((unsigned int)h << 16);
}

// ---------------- CSR build: bucketed, no global random scatter (R8-proven, best run) ----------------

__global__ __launch_bounds__(256) void bin_count(const int* __restrict__ ei, int E,
                                                 int* __restrict__ bcnt, int nbuck) {
    __shared__ int h[MAXB];
    for (int i = threadIdx.x; i < nbuck; i += 256) h[i] = 0;
    __syncthreads();
    int i = blockIdx.x * 256 + threadIdx.x, stride = gridDim.x * 256;
    for (int e = i; e < E; e += stride) {
        int d = ei[E + e];
        atomicAdd(&h[d >> 8], 1);
    }
    __syncthreads();
    for (int b = threadIdx.x; b < nbuck; b += 256)
        if (h[b]) atomicAdd(&bcnt[b], h[b]);
}

__global__ __launch_bounds__(512) void scan_small(const int* __restrict__ bcnt,
                                                  int* __restrict__ boff,
                                                  int* __restrict__ bpos,
                                                  int* __restrict__ row_ptr_end,
                                                  int nbuck, int E) {
    __shared__ int wsum[8];
    int tid = threadIdx.x, lane = tid & 63, wv = tid >> 6;
    int val = (tid < nbuck) ? bcnt[tid] : 0;
    int s = val;
#pragma unroll
    for (int off = 1; off < 64; off <<= 1) {
        int t = __shfl_up(s, off, 64);
        if (lane >= off) s += t;
    }
    if (lane == 63) wsum[wv] = s;
    __syncthreads();
    if (wv == 0) {
        int t = (lane < 8) ? wsum[lane] : 0;
#pragma unroll
        for (int off = 1; off < 8; off <<= 1) {
            int u = __shfl_up(t, off, 64);
            if (lane >= off) t += u;
        }
        if (lane < 8) wsum[lane] = t;
    }
    __syncthreads();
    int excl = ((wv == 0) ? 0 : wsum[wv - 1]) + s - val;
    if (tid < nbuck) { boff[tid] = excl; bpos[tid] = excl; }
    if (tid == 0) { boff[nbuck] = E; *row_ptr_end = E; }
}

// 4K-edge chunks -> 391 blocks (write-amp ~1.6x, good occupancy; R8-proven)
__global__ __launch_bounds__(256) void bin_scatter(const int* __restrict__ ei, int E,
                                                   int* __restrict__ bpos,
                                                   int* __restrict__ binned, int nbuck) {
    __shared__ int h[MAXB];
    __shared__ int res[MAXB];
    int base = blockIdx.x * CHUNK;
    int cnt = min(CHUNK, E - base);
    int tid = threadIdx.x;
    for (int b = tid; b < nbuck; b += 256) h[b] = 0;
    __syncthreads();
    for (int k = tid; k < cnt; k += 256) {
        int d = ei[E + base + k];
        atomicAdd(&h[d >> 8], 1);
    }
    __syncthreads();
    for (int b = tid; b < nbuck; b += 256) {
        int c = h[b];
        res[b] = c ? atomicAdd(&bpos[b], c) : 0;
        h[b] = 0;  // reuse as rank counter
    }
    __syncthreads();
    for (int k = tid; k < cnt; k += 256) {
        int srcv = ei[base + k];
        int d = ei[E + base + k];
        int b = d >> 8;
        int r = atomicAdd(&h[b], 1);
        binned[res[b] + r] = ((d & 255) << 17) | srcv;  // src < 2^17
    }
}

// one workgroup per 256-node bucket: counts -> scan -> row_ptr + ranked esrc
__global__ __launch_bounds__(256) void bucket_csr(const int* __restrict__ binned,
                                                  const int* __restrict__ boff,
                                                  int* __restrict__ row_ptr,
                                                  int* __restrict__ esrc, int N) {
    __shared__ int ncnt[256];
    __shared__ int npos[256];
    __shared__ int wsum[4];
    int b = blockIdx.x, tid = threadIdx.x, lane = tid & 63, wv = tid >> 6;
    int lo = boff[b], hi = boff[b + 1];
    int base_node = b << 8;
    ncnt[tid] = 0;
    __syncthreads();
    for (int i = lo + tid; i < hi; i += 256)
        atomicAdd(&ncnt[binned[i] >> 17], 1);
    __syncthreads();
    int c = ncnt[tid];
    int s = c;
#pragma unroll
    for (int off = 1; off < 64; off <<= 1) {
        int t = __shfl_up(s, off, 64);
        if (lane >= off) s += t;
    }
    if (lane == 63) wsum[wv] = s;
    __syncthreads();
    int woff = 0;
#pragma unroll
    for (int i = 0; i < 4; i++) woff += (i < wv) ? wsum[i] : 0;
    int abspos = lo + woff + (s - c);
    if (base_node + tid < N) row_ptr[base_node + tid] = abspos;
    npos[tid] = abspos;
    __syncthreads();
    for (int i = lo + tid; i < hi; i += 256) {
        int val = binned[i];
        int r = atomicAdd(&npos[val >> 17], 1);
        esrc[r] = val & 0x1FFFF;
    }
}

// ---------------- dense: Y[n][64](bf16) = X[n][K](f32) @ W[64][K]^T ----------------
template <int K>
__global__ __launch_bounds__(256) void linear_kernel(const float* __restrict__ X,
                                                     const float* __restrict__ W,
                                                     unsigned short* __restrict__ Y, int N) {
    __shared__ float wlds[K * 64];
    __shared__ float xlds[16 * K];
    int tid = threadIdx.x;
    for (int j = tid; j < 64 * K; j += 256) {
        int o = j / K, k = j % K;
        wlds[(k >> 2) * 256 + o * 4 + (k & 3)] = W[j];
    }
    __syncthreads();
    const float4* w4p = (const float4*)wlds;
    const float4* x4p = (const float4*)xlds;
    int wv = tid >> 6, lane = tid & 63;
    for (int nb = blockIdx.x * 16; nb < N; nb += gridDim.x * 16) {
        const float4* xg = (const float4*)(X + (size_t)nb * K);
        float4* xl = (float4*)xlds;
        for (int j = tid; j < 16 * K / 4; j += 256) xl[j] = xg[j];
        __syncthreads();
        int r = wv * 4;
        float a0 = 0.f, a1 = 0.f, a2 = 0.f, a3 = 0.f;
#pragma unroll 8
        for (int kb = 0; kb < K / 4; kb++) {
            float4 w = w4p[kb * 64 + lane];
            float4 x0 = x4p[(r + 0) * (K / 4) + kb];
            float4 x1 = x4p[(r + 1) * (K / 4) + kb];
            float4 x2 = x4p[(r + 2) * (K / 4) + kb];
            float4 x3 = x4p[(r + 3) * (K / 4) + kb];
            a0 += x0.x * w.x + x0.y * w.y + x0.z * w.z + x0.w * w.w;
            a1 += x1.x * w.x + x1.y * w.y + x1.z * w.z + x1.w * w.w;
            a2 += x2.x * w.x + x2.y * w.y + x2.z * w.z + x2.w * w.w;
            a3 += x3.x * w.x + x3.y * w.y + x3.z * w.z + x3.w * w.w;
        }
        Y[(size_t)(nb + r + 0) * 64 + lane] = f2bf(a0);
        Y[(size_t)(nb + r + 1) * 64 + lane] = f2bf(a1);
        Y[(size_t)(nb + r + 2) * 64 + lane] = f2bf(a2);
        Y[(size_t)(nb + r + 3) * 64 + lane] = f2bf(a3);
        __syncthreads();
    }
}

// ---------------- gather: T[i](bf16) = relu(Y[i] + bias + sum_{e} Y[src[e]]) ----------------
// one wave per node, 25K blocks, 20 VGPRs, 67% occupancy — request-rate floor
// (time = 29ns x 1.6M wave-row-requests + 0.14us/MB x FETCH; L2-capacity miss model
//  predicts 141MB vs 154MB measured)
__global__ __launch_bounds__(256) void gather_kernel(const unsigned short* __restrict__ Y,
                                                     const int* __restrict__ row_ptr,
                                                     const int* __restrict__ esrc,
                                                     const float* __restrict__ bias,
                                                     unsigned short* __restrict__ T, int N) {
    int wv = threadIdx.x >> 6, lane = threadIdx.x & 63;
    int node = blockIdx.x * 4 + wv;
    if (node >= N) return;
    float acc = bf2f(Y[(size_t)node * 64 + lane]) + bias[lane];
    int e0 = row_ptr[node], e1 = row_ptr[node + 1];
    int e = e0;
    for (; e + 8 <= e1; e += 8) {
        int s0 = esrc[e], s1 = esrc[e + 1], s2 = esrc[e + 2], s3 = esrc[e + 3];
        int s4 = esrc[e + 4], s5 = esrc[e + 5], s6 = esrc[e + 6], s7 = esrc[e + 7];
        float f0 = bf2f(Y[(size_t)s0 * 64 + lane]);
        float f1 = bf2f(Y[(size_t)s1 * 64 + lane]);
        float f2 = bf2f(Y[(size_t)s2 * 64 + lane]);
        float f3 = bf2f(Y[(size_t)s3 * 64 + lane]);
        float f4 = bf2f(Y[(size_t)s4 * 64 + lane]);
        float f5 = bf2f(Y[(size_t)s5 * 64 + lane]);
        float f6 = bf2f(Y[(size_t)s6 * 64 + lane]);
        float f7 = bf2f(Y[(size_t)s7 * 64 + lane]);
        acc += ((f0 + f1) + (f2 + f3)) + ((f4 + f5) + (f6 + f7));
    }
    for (; e < e1; e++) acc += bf2f(Y[(size_t)esrc[e] * 64 + lane]);
    T[(size_t)node * 64 + lane] = f2bf(fmaxf(acc, 0.f));
}

// stage 16 nodes x 64 feats of bf16 into f32 LDS tile
__device__ __forceinline__ void stage_bf16_tile(const unsigned short* __restrict__ src,
                                                float* __restrict__ dst, int tid) {
    const ushort4* s4 = (const ushort4*)src;
    ushort4 u = s4[tid];  // 256 threads x 4 elems = 1024
    float4* d4 = (float4*)dst;
    d4[tid] = make_float4(bf2f(u.x), bf2f(u.y), bf2f(u.z), bf2f(u.w));
}

// ---------------- fused: Y(bf16) = (relu(bn(T@W1^T + b1))) @ W2^T ----------------
__global__ __launch_bounds__(256) void fused_mlp2_kernel(
    const unsigned short* __restrict__ T, const float* __restrict__ W1,
    const float* __restrict__ b1, const float* __restrict__ g, const float* __restrict__ be,
    const float* __restrict__ m, const float* __restrict__ v, const float* __restrict__ W2,
    unsigned short* __restrict__ Y, int N) {
    __shared__ float w1lds[64 * 64];
    __shared__ float w2lds[64 * 64];
    __shared__ float tl[16 * 64];
    __shared__ float hl[16 * 64];
    int tid = threadIdx.x, wv = tid >> 6, lane = tid & 63;
    for (int j = tid; j < 4096; j += 256) {
        int o = j >> 6, k = j & 63;
        int idx = (k >> 2) * 256 + o * 4 + (k & 3);
        w1lds[idx] = W1[j];
        w2lds[idx] = W2[j];
    }
    float bias = b1[lane];
    float s = g[lane] * rsqrtf(v[lane] + BN_EPS);
    float c = be[lane] - m[lane] * s;
    __syncthreads();
    const float4* w14 = (const float4*)w1lds;
    const float4* w24 = (const float4*)w2lds;
    const float4* t4 = (const float4*)tl;
    const float4* h4 = (const float4*)hl;
    for (int nb = blockIdx.x * 16; nb < N; nb += gridDim.x * 16) {
        stage_bf16_tile(T + (size_t)nb * 64, tl, tid);
        __syncthreads();
        int r = wv * 4;
        float a0 = bias, a1 = bias, a2 = bias, a3 = bias;
#pragma unroll
        for (int kb = 0; kb < 16; kb++) {
            float4 w = w14[kb * 64 + lane];
            float4 x0 = t4[(r + 0) * 16 + kb];
            float4 x1 = t4[(r + 1) * 16 + kb];
            float4 x2 = t4[(r + 2) * 16 + kb];
            float4 x3 = t4[(r + 3) * 16 + kb];
            a0 += x0.x * w.x + x0.y * w.y + x0.z * w.z + x0.w * w.w;
            a1 += x1.x * w.x + x1.y * w.y + x1.z * w.z + x1.w * w.w;
            a2 += x2.x * w.x + x2.y * w.y + x2.z * w.z + x2.w * w.w;
            a3 += x3.x * w.x + x3.y * w.y + x3.z * w.z + x3.w * w.w;
        }
        a0 = fmaxf(a0 * s + c, 0.f);
        a1 = fmaxf(a1 * s + c, 0.f);
        a2 = fmaxf(a2 * s + c, 0.f);
        a3 = fmaxf(a3 * s + c, 0.f);
        hl[(r + 0) * 64 + lane] = a0;
        hl[(r + 1) * 64 + lane] = a1;
        hl[(r + 2) * 64 + lane] = a2;
        hl[(r + 3) * 64 + lane] = a3;
        __syncthreads();
        float o0 = 0.f, o1 = 0.f, o2 = 0.f, o3 = 0.f;
#pragma unroll
        for (int kb = 0; kb < 16; kb++) {
            float4 w = w24[kb * 64 + lane];
            float4 x0 = h4[(r + 0) * 16 + kb];
            float4 x1 = h4[(r + 1) * 16 + kb];
            float4 x2 = h4[(r + 2) * 16 + kb];
            float4 x3 = h4[(r + 3) * 16 + kb];
            o0 += x0.x * w.x + x0.y * w.y + x0.z * w.z + x0.w * w.w;
            o1 += x1.x * w.x + x1.y * w.y + x1.z * w.z + x1.w * w.w;
            o2 += x2.x * w.x + x2.y * w.y + x2.z * w.z + x2.w * w.w;
            o3 += x3.x * w.x + x3.y * w.y + x3.z * w.z + x3.w * w.w;
        }
        Y[(size_t)(nb + r + 0) * 64 + lane] = f2bf(o0);
        Y[(size_t)(nb + r + 1) * 64 + lane] = f2bf(o1);
        Y[(size_t)(nb + r + 2) * 64 + lane] = f2bf(o2);
        Y[(size_t)(nb + r + 3) * 64 + lane] = f2bf(o3);
        __syncthreads();
    }
}

// ---------------- H(bf16) = relu(bn(T@W^T + b)) ----------------
__global__ __launch_bounds__(256) void fused_mlp1_kernel(
    const unsigned short* __restrict__ T, const float* __restrict__ W,
    const float* __restrict__ b, const float* __restrict__ g, const float* __restrict__ be,
    const float* __restrict__ m, const float* __restrict__ v,
    unsigned short* __restrict__ H, int N) {
    __shared__ float wlds[64 * 64];
    __shared__ float tl[16 * 64];
    int tid = threadIdx.x, wv = tid >> 6, lane = tid & 63;
    for (int j = tid; j < 4096; j += 256) {
        int o = j >> 6, k = j & 63;
        wlds[(k >> 2) * 256 + o * 4 + (k & 3)] = W[j];
    }
    float bias = b[lane];
    float s = g[lane] * rsqrtf(v[lane] + BN_EPS);
    float c = be[lane] - m[lane] * s;
    __syncthreads();
    const float4* w4 = (const float4*)wlds;
    const float4* t4 = (const float4*)tl;
    for (int nb = blockIdx.x * 16; nb < N; nb += gridDim.x * 16) {
        stage_bf16_tile(T + (size_t)nb * 64, tl, tid);
        __syncthreads();
        int r = wv * 4;
        float a0 = bias, a1 = bias, a2 = bias, a3 = bias;
#pragma unroll
        for (int kb = 0; kb < 16; kb++) {
            float4 w = w4[kb * 64 + lane];
            float4 x0 = t4[(r + 0) * 16 + kb];
            float4 x1 = t4[(r + 1) * 16 + kb];
            float4 x2 = t4[(r + 2) * 16 + kb];
            float4 x3 = t4[(r + 3) * 16 + kb];
            a0 += x0.x * w.x + x0.y * w.y + x0.z * w.z + x0.w * w.w;
            a1 += x1.x * w.x + x1.y * w.y + x1.z * w.z + x1.w * w.w;
            a2 += x2.x * w.x + x2.y * w.y + x2.z * w.z + x2.w * w.w;
            a3 += x3.x * w.x + x3.y * w.y + x3.z * w.z + x3.w * w.w;
        }
        H[(size_t)(nb + r + 0) * 64 + lane] = f2bf(fmaxf(a0 * s + c, 0.f));
        H[(size_t)(nb + r + 1) * 64 + lane] = f2bf(fmaxf(a1 * s + c, 0.f));
        H[(size_t)(nb + r + 2) * 64 + lane] = f2bf(fmaxf(a2 * s + c, 0.f));
        H[(size_t)(nb + r + 3) * 64 + lane] = f2bf(fmaxf(a3 * s + c, 0.f));
        __syncthreads();
    }
}

// ---------------- mean pool per graph (batch is sorted) ----------------
__global__ __launch_bounds__(256) void pool_kernel(const unsigned short* __restrict__ H,
                                                   const int* __restrict__ batch,
                                                   float* __restrict__ out, int N) {
    __shared__ float part[4][64];
    int g = blockIdx.x;
    int tid = threadIdx.x, wv = tid >> 6, lane = tid & 63;
    int lo = 0, hi = N;
    while (lo < hi) { int mid = (lo + hi) >> 1; if (batch[mid] < g) lo = mid + 1; else hi = mid; }
    int start = lo;
    hi = N;
    while (lo < hi) { int mid = (lo + hi) >> 1; if (batch[mid] < g + 1) lo = mid + 1; else hi = mid; }
    int end = lo;
    float acc = 0.f;
    for (int i = start + wv; i < end; i += 4) acc += bf2f(H[(size_t)i * 64 + lane]);
    part[wv][lane] = acc;
    __syncthreads();
    if (tid < 64) {
        float sfin = part[0][tid] + part[1][tid] + part[2][tid] + part[3][tid];
        float cnt = (float)(end - start);
        out[(size_t)g * 64 + tid] = sfin / fmaxf(cnt, 1.f);
    }
}

extern "C" void kernel_launch(void* const* d_in, const int* in_sizes, int n_in,
                              void* d_out, int out_size, void* d_ws, size_t ws_size,
                              hipStream_t stream) {
    const float* x   = (const float*)d_in[0];
    const int*   ei  = (const int*)d_in[1];
    const int*   bat = (const int*)d_in[2];
    const float* W1a = (const float*)d_in[3];
    const float* b1a = (const float*)d_in[4];
    const float* W1b = (const float*)d_in[5];
    const float* b1b = (const float*)d_in[6];
    const float* g1  = (const float*)d_in[7];
    const float* be1 = (const float*)d_in[8];
    const float* m1  = (const float*)d_in[9];
    const float* v1  = (const float*)d_in[10];
    const float* W2a = (const float*)d_in[11];
    const float* b2a = (const float*)d_in[12];
    const float* W2b = (const float*)d_in[13];
    const float* b2b = (const float*)d_in[14];
    const float* g2  = (const float*)d_in[15];
    const float* be2 = (const float*)d_in[16];
    const float* m2  = (const float*)d_in[17];
    const float* v2  = (const float*)d_in[18];
    float* out = (float*)d_out;

    int N = in_sizes[0] / 128;
    int E = in_sizes[1] / 2;
    int G = out_size / 64;
    int nbuck = (N + 255) >> 8;

    // workspace layout (bf16 feature buffers)
    char* ws = (char*)d_ws;
    int* row_ptr = (int*)ws;                              // N+1 (padded)
    int* bcnt = row_ptr + ((N + 1 + 3) & ~3);             // MAXB
    int* boff = bcnt + MAXB;                              // MAXB+1
    int* bpos = boff + MAXB + 4;                          // MAXB
    int* esrc = bpos + MAXB;                              // E
    unsigned short* bufA = (unsigned short*)(esrc + E);   // N*64 bf16
    unsigned short* bufB = bufA + (size_t)N * 64;         // N*64 bf16
    int* binned = (int*)bufB;                             // aliases bufB (dead until gather#1)

    // CSR build
    hipMemsetAsync(bcnt, 0, MAXB * sizeof(int), stream);
    bin_count<<<512, 256, 0, stream>>>(ei, E, bcnt, nbuck);
    scan_small<<<1, 512, 0, stream>>>(bcnt, boff, bpos, row_ptr + N, nbuck, E);
    bin_scatter<<<(E + CHUNK - 1) / CHUNK, 256, 0, stream>>>(ei, E, bpos, binned, nbuck);
    bucket_csr<<<nbuck, 256, 0, stream>>>(binned, boff, row_ptr, esrc, N);

    // layer 1
    linear_kernel<128><<<2048, 256, 0, stream>>>(x, W1a, bufA, N);
    gather_kernel<<<(N + 3) / 4, 256, 0, stream>>>(bufA, row_ptr, esrc, b1a, bufB, N);
    fused_mlp2_kernel<<<2048, 256, 0, stream>>>(bufB, W1b, b1b, g1, be1, m1, v1, W2a, bufA, N);

    // layer 2
    gather_kernel<<<(N + 3) / 4, 256, 0, stream>>>(bufA, row_ptr, esrc, b2a, bufB, N);
    fused_mlp1_kernel<<<2048, 256, 0, stream>>>(bufB, W2b, b2b, g2, be2, m2, v2, bufA, N);

    // mean pool
    pool_kernel<<<G, 256, 0, stream>>>(bufA, bat, out, N);
}